// Round 9
// baseline (135.473 us; speedup 1.0000x reference)
//
#include <hip/hip_runtime.h>
#include <math.h>

#define BB 64
#define NN 2048
#define DZ 128
#define DA 64
#define DD 192
#define EE 16
#define HH 512
#define LN_EPS 1e-5f

typedef __attribute__((ext_vector_type(8))) short short8;
typedef __attribute__((ext_vector_type(4))) float f32x4;

__device__ __forceinline__ float mishf(float x) {
    float sp = (x > 20.f) ? x : log1pf(__expf(x));
    return x * tanhf(sp);
}

__device__ __forceinline__ unsigned short bf16_rne(float f) {
    unsigned u = __float_as_uint(f);
    return (unsigned short)((u + 0x7FFFu + ((u >> 16) & 1u)) >> 16);
}
__device__ __forceinline__ float bf16f(unsigned short h) {
    return __uint_as_float(((unsigned)h) << 16);
}

// async global->LDS, 16B per lane: writes lds_base + lane*16, reads per-lane gptr
__device__ __forceinline__ void gload_lds16(const float* g, float* l) {
    __builtin_amdgcn_global_load_lds(
        (const __attribute__((address_space(1))) void*)g,
        (__attribute__((address_space(3))) void*)l, 16, 0, 0);
}

// ---------------- phi pre-pack: per-lane MFMA B-fragments, bf16 hi/lo ----------------
// layout: [kk<6][lane<64][j<8];  lane: e = lane&15 (col), g = lane>>4; k = kk*32+g*8+j
__global__ __launch_bounds__(256)
void k_phipack(const float* __restrict__ phi, unsigned short* __restrict__ ph,
               unsigned short* __restrict__ pl) {
    int idx = blockIdx.x * 256 + threadIdx.x;      // < 3072
    if (idx >= 6 * 64 * 8) return;
    int j = idx & 7, lane = (idx >> 3) & 63, kk = idx >> 9;
    int e = lane & 15, g = lane >> 4;
    int d = kk * 32 + g * 8 + j;
    float f = phi[d * EE + e];
    unsigned short h = bf16_rne(f);
    ph[idx] = h;
    pl[idx] = bf16_rne(f - bf16f(h));
}

// ---------------- K1: weights = x @ phi via split-bf16 MFMA ----------------
__global__ __launch_bounds__(256)
void k_weights(const float* __restrict__ z, const float* __restrict__ a,
               const unsigned short* __restrict__ php,
               const unsigned short* __restrict__ plp,
               float* __restrict__ w) {
    int t = threadIdx.x;
    int wv = t >> 6, l = t & 63;
    long tokbase = ((long)blockIdx.x * 4 + wv) * 16;
    long tokA = tokbase + (l & 15);
    int g = l >> 4;

    short8 bh[6], bl[6], ah[6], al[6];
#pragma unroll
    for (int kk = 0; kk < 6; kk++) {
        bh[kk] = *(const short8*)(php + kk * 512 + l * 8);
        bl[kk] = *(const short8*)(plp + kk * 512 + l * 8);
    }
#pragma unroll
    for (int kk = 0; kk < 6; kk++) {
        int d0 = kk * 32 + g * 8;                  // 8-elem chunk never straddles z/a
        const float* src = (d0 < DZ) ? (z + tokA * DZ + d0)
                                     : (a + tokA * DA + (d0 - DZ));
        float4 v0 = ((const float4*)src)[0];
        float4 v1 = ((const float4*)src)[1];
        float f[8] = {v0.x, v0.y, v0.z, v0.w, v1.x, v1.y, v1.z, v1.w};
#pragma unroll
        for (int j = 0; j < 8; j++) {
            unsigned short h = bf16_rne(f[j]);
            ah[kk][j] = (short)h;
            al[kk][j] = (short)bf16_rne(f[j] - bf16f(h));
        }
    }

    f32x4 acc = {0.f, 0.f, 0.f, 0.f};
#pragma unroll
    for (int kk = 0; kk < 6; kk++)
        acc = __builtin_amdgcn_mfma_f32_16x16x32_bf16(ah[kk], bh[kk], acc, 0, 0, 0);
#pragma unroll
    for (int kk = 0; kk < 6; kk++)
        acc = __builtin_amdgcn_mfma_f32_16x16x32_bf16(al[kk], bh[kk], acc, 0, 0, 0);
#pragma unroll
    for (int kk = 0; kk < 6; kk++)
        acc = __builtin_amdgcn_mfma_f32_16x16x32_bf16(ah[kk], bl[kk], acc, 0, 0, 0);

    int e = l & 15;                                 // D: col = lane&15
#pragma unroll
    for (int r = 0; r < 4; r++) {
        long row = tokbase + g * 4 + r;             // D: row = (lane>>4)*4 + r
        w[row * EE + e] = acc[r];
    }
}

// ---------------- K2: softmax stats over n, chunked ----------------
#define RSTR 17
__global__ __launch_bounds__(256)
void k_stats1(const float* __restrict__ w, float* __restrict__ lmax,
              float* __restrict__ lsum) {
    __shared__ float red[256 * RSTR];
    int b = blockIdx.y, c = blockIdx.x, t = threadIdx.x;
    const float* wb = w + ((long)b * NN + c * 512) * EE;

    float m[EE];
#pragma unroll
    for (int e = 0; e < EE; e++) m[e] = -1e30f;
    for (int k = 0; k < 2; k++) {
        const float4* row = (const float4*)(wb + ((long)(k * 256 + t)) * EE);
#pragma unroll
        for (int q = 0; q < 4; q++) {
            float4 v = row[q];
            m[q * 4 + 0] = fmaxf(m[q * 4 + 0], v.x);
            m[q * 4 + 1] = fmaxf(m[q * 4 + 1], v.y);
            m[q * 4 + 2] = fmaxf(m[q * 4 + 2], v.z);
            m[q * 4 + 3] = fmaxf(m[q * 4 + 3], v.w);
        }
    }
#pragma unroll
    for (int e = 0; e < EE; e++) red[t * RSTR + e] = m[e];
    __syncthreads();
    for (int s = 128; s > 0; s >>= 1) {
        if (t < s) {
#pragma unroll
            for (int e = 0; e < EE; e++)
                red[t * RSTR + e] = fmaxf(red[t * RSTR + e], red[(t + s) * RSTR + e]);
        }
        __syncthreads();
    }
    float mg[EE];
#pragma unroll
    for (int e = 0; e < EE; e++) mg[e] = red[e];
    __syncthreads();

    float s_[EE];
#pragma unroll
    for (int e = 0; e < EE; e++) s_[e] = 0.f;
    for (int k = 0; k < 2; k++) {
        const float4* row = (const float4*)(wb + ((long)(k * 256 + t)) * EE);
#pragma unroll
        for (int q = 0; q < 4; q++) {
            float4 v = row[q];
            s_[q * 4 + 0] += __expf(v.x - mg[q * 4 + 0]);
            s_[q * 4 + 1] += __expf(v.y - mg[q * 4 + 1]);
            s_[q * 4 + 2] += __expf(v.z - mg[q * 4 + 2]);
            s_[q * 4 + 3] += __expf(v.w - mg[q * 4 + 3]);
        }
    }
#pragma unroll
    for (int e = 0; e < EE; e++) red[t * RSTR + e] = s_[e];
    __syncthreads();
    for (int s = 128; s > 0; s >>= 1) {
        if (t < s) {
#pragma unroll
            for (int e = 0; e < EE; e++)
                red[t * RSTR + e] += red[(t + s) * RSTR + e];
        }
        __syncthreads();
    }
    if (t < EE) {
        lmax[((long)b * 4 + c) * EE + t] = mg[t];
        lsum[((long)b * 4 + c) * EE + t] = red[t];
    }
}

__global__ __launch_bounds__(256)
void k_stats2(const float* __restrict__ lmax, const float* __restrict__ lsum,
              float* __restrict__ gmax, float* __restrict__ grcp) {
    int idx = blockIdx.x * 256 + threadIdx.x;
    if (idx >= BB * EE) return;
    int b = idx >> 4, e = idx & 15;
    float gm = -1e30f;
#pragma unroll
    for (int c = 0; c < 4; c++)
        gm = fmaxf(gm, lmax[((long)b * 4 + c) * EE + e]);
    float Z = 0.f;
#pragma unroll
    for (int c = 0; c < 4; c++)
        Z += __expf(lmax[((long)b * 4 + c) * EE + e] - gm) * lsum[((long)b * 4 + c) * EE + e];
    gmax[idx] = gm;
    grcp[idx] = 1.f / Z;
}

// ---------------- K3: xin = disp^T @ x via split-bf16 MFMA, LDS-staged ----------------
// Padded LDS segment strides (floats per 1KB segment) -> <=2-way bank alias (free),
// 16B-aligned stage destinations. One barrier per kk: stage(next); compute(cur); bar.
#define SEGZ 260
#define SEGA 260
#define SEGW 272
__global__ __launch_bounds__(256)
void k_xin2(const float* __restrict__ z, const float* __restrict__ a,
            const float* __restrict__ w, const float* __restrict__ lmax,
            const float* __restrict__ lsum, float* __restrict__ pxin) {
    __shared__ float zs[2][16 * SEGZ];   // 33.3 KB
    __shared__ float as_[2][8 * SEGA];   // 16.6 KB
    __shared__ float ws_[2][2 * SEGW];   //  4.3 KB
    int kq = blockIdx.x, b = blockIdx.y;
    int t = threadIdx.x, wv = t >> 6, l = t & 63;
    int g = l >> 4, c = l & 15;

    // inline softmax-stat combine for e = c (replaces k_stats2)
    float gm = -1e30f;
#pragma unroll
    for (int cc = 0; cc < 4; cc++)
        gm = fmaxf(gm, lmax[((long)b * 4 + cc) * EE + c]);
    float Zs = 0.f;
#pragma unroll
    for (int cc = 0; cc < 4; cc++)
        Zs += __expf(lmax[((long)b * 4 + cc) * EE + c] - gm)
            * lsum[((long)b * 4 + cc) * EE + c];
    float gr = 1.f / Zs;

    const float* zb = z + ((long)b * NN + (long)kq * 128) * DZ;  // 64 KB contiguous
    const float* ab = a + ((long)b * NN + (long)kq * 128) * DA;  // 32 KB contiguous
    const float* wb = w + ((long)b * NN + (long)kq * 128) * EE;  //  8 KB contiguous

    auto stage = [&](int kk, int bf) {
#pragma unroll
        for (int s = 0; s < 4; s++) {
            int seg = wv * 4 + s;
            gload_lds16(zb + kk * 4096 + seg * 256 + l * 4, &zs[bf][seg * SEGZ]);
        }
#pragma unroll
        for (int s = 0; s < 2; s++) {
            int seg = wv * 2 + s;
            gload_lds16(ab + kk * 2048 + seg * 256 + l * 4, &as_[bf][seg * SEGA]);
        }
        if (wv < 2)
            gload_lds16(wb + kk * 512 + wv * 256 + l * 4, &ws_[bf][wv * SEGW]);
    };

    f32x4 acc0 = {0.f, 0.f, 0.f, 0.f};
    f32x4 acc1 = {0.f, 0.f, 0.f, 0.f};
    f32x4 acc2 = {0.f, 0.f, 0.f, 0.f};

    stage(0, 0);
    __syncthreads();                       // drain stage(0)
#pragma unroll
    for (int kk = 0; kk < 4; kk++) {
        int bf = kk & 1;
        if (kk < 3) stage(kk + 1, bf ^ 1); // issue next-tile loads (stay in flight)

        // A: dispatch fragment, row = e = c, k-slot n = g*8+j
        short8 ad;
#pragma unroll
        for (int j = 0; j < 8; j++) {
            int n = g * 8 + j;
            float wvv = ws_[bf][(n >> 4) * SEGW + (n & 15) * 16 + c];
            ad[j] = (short)bf16_rne(__expf(wvv - gm) * gr);
        }
        // B: three d-tiles per wave, col = d = (wv*3+i)*16 + c, split hi/lo
#pragma unroll
        for (int i = 0; i < 3; i++) {
            int d = (wv * 3 + i) * 16 + c;
            short8 xh_, xl_;
#pragma unroll
            for (int j = 0; j < 8; j++) {
                int n = g * 8 + j;
                float f = (d < DZ)
                    ? zs[bf][(n >> 1) * SEGZ + (n & 1) * 128 + d]
                    : as_[bf][(n >> 2) * SEGA + (n & 3) * 64 + (d - DZ)];
                unsigned short h = bf16_rne(f);
                xh_[j] = (short)h;
                xl_[j] = (short)bf16_rne(f - bf16f(h));
            }
            if (i == 0) {
                acc0 = __builtin_amdgcn_mfma_f32_16x16x32_bf16(ad, xh_, acc0, 0, 0, 0);
                acc0 = __builtin_amdgcn_mfma_f32_16x16x32_bf16(ad, xl_, acc0, 0, 0, 0);
            } else if (i == 1) {
                acc1 = __builtin_amdgcn_mfma_f32_16x16x32_bf16(ad, xh_, acc1, 0, 0, 0);
                acc1 = __builtin_amdgcn_mfma_f32_16x16x32_bf16(ad, xl_, acc1, 0, 0, 0);
            } else {
                acc2 = __builtin_amdgcn_mfma_f32_16x16x32_bf16(ad, xh_, acc2, 0, 0, 0);
                acc2 = __builtin_amdgcn_mfma_f32_16x16x32_bf16(ad, xl_, acc2, 0, 0, 0);
            }
        }
        __syncthreads();   // drains next-stage loads AND retires reads of bf
    }

    // D: col = d-in-tile = c, row = e = g*4 + r.  pxin[kq][e*BB+b][DD]
    float* pb = pxin + (long)kq * (EE * BB * DD) + (long)b * DD;
#pragma unroll
    for (int r = 0; r < 4; r++) {
        int e = g * 4 + r;
        float* pr = pb + (long)e * (BB * DD);
        pr[(wv * 3 + 0) * 16 + c] = acc0[r];
        pr[(wv * 3 + 1) * 16 + c] = acc1[r];
        pr[(wv * 3 + 2) * 16 + c] = acc2[r];
    }
}

// ---------------- K3 fallback (atomic, small-ws) ----------------
__global__ __launch_bounds__(192)
void k_xin_scalar(const float* __restrict__ z, const float* __restrict__ a,
                  const float* __restrict__ w, const float* __restrict__ gmax,
                  const float* __restrict__ grcp, float* __restrict__ dst) {
    __shared__ float disp[128 * EE];
    int b = blockIdx.y, chunk = blockIdx.x, t = threadIdx.x;

    const float* wrow = w + ((long)b * NN + (long)chunk * 128) * EE;
    for (int i = t; i < 128 * EE; i += 192) {
        int e = i & 15;
        disp[i] = __expf(wrow[i] - gmax[b * EE + e]) * grcp[b * EE + e];
    }
    __syncthreads();

    const float* xp;
    int stride;
    if (t < DZ) { xp = z + ((long)b * NN + (long)chunk * 128) * DZ + t; stride = DZ; }
    else        { xp = a + ((long)b * NN + (long)chunk * 128) * DA + (t - DZ); stride = DA; }

    float acc[EE];
#pragma unroll
    for (int e = 0; e < EE; e++) acc[e] = 0.f;

    for (int n = 0; n < 128; n++) {
        float xv = xp[(long)n * stride];
        const float4* dp = (const float4*)(disp + n * EE);
#pragma unroll
        for (int q = 0; q < 4; q++) {
            float4 p = dp[q];
            acc[q * 4 + 0] += p.x * xv;
            acc[q * 4 + 1] += p.y * xv;
            acc[q * 4 + 2] += p.z * xv;
            acc[q * 4 + 3] += p.w * xv;
        }
    }
#pragma unroll
    for (int e = 0; e < EE; e++)
        atomicAdd(&dst[((long)e * BB + b) * DD + t], acc[e]);
}

// reduce 16 partials -> xin[e][b][d]
__global__ __launch_bounds__(256)
void k_xinred(const float* __restrict__ xinp, float* __restrict__ xin) {
    long i = (long)blockIdx.x * 256 + threadIdx.x;   // < EE*BB*DD = 196608
    float s = 0.f;
#pragma unroll
    for (int c = 0; c < 16; c++)
        s += xinp[(long)c * (EE * BB * DD) + i];
    xin[i] = s;
}

// ---------------- Split-K per-expert GEMM ----------------
template<int K, int OUT, int KSLICE, bool ADD_BIAS>
__global__ __launch_bounds__(256)
void k_gemm(const float* __restrict__ X, const float* __restrict__ W,
            const float* __restrict__ bias, float* __restrict__ Yp) {
    constexpr int SP = KSLICE + 4;
    constexpr int K4 = KSLICE / 4;
    __shared__ float xs[64 * SP];

    int cb = blockIdx.x, ks = blockIdx.y, e = blockIdx.z;
    int t = threadIdx.x;
    int k0 = ks * KSLICE;

    for (int i = t; i < 64 * K4; i += 256) {
        int r = i / K4, k4 = i % K4;
        *(float4*)&xs[r * SP + k4 * 4] =
            *(const float4*)(X + ((long)e * BB + r) * K + k0 + k4 * 4);
    }
    __syncthreads();

    int c = cb * 32 + (t & 7) * 4;
    int r0 = (t >> 3) * 2;
    const float* Wp = W + ((long)e * K + k0) * OUT + c;

    float acc0[4], acc1[4];
#pragma unroll
    for (int j = 0; j < 4; j++) {
        float bv = ADD_BIAS ? bias[(long)e * OUT + c + j] : 0.f;
        acc0[j] = bv;
        acc1[j] = bv;
    }

#pragma unroll 4
    for (int k4 = 0; k4 < K4; k4++) {
        float4 x0 = *(const float4*)&xs[r0 * SP + k4 * 4];
        float4 x1 = *(const float4*)&xs[(r0 + 1) * SP + k4 * 4];
        const float* xp0 = &x0.x;
        const float* xp1 = &x1.x;
#pragma unroll
        for (int j = 0; j < 4; j++) {
            float4 wv = *(const float4*)(Wp + (long)(k4 * 4 + j) * OUT);
            float xa = xp0[j], xb = xp1[j];
            acc0[0] += xa * wv.x; acc0[1] += xa * wv.y;
            acc0[2] += xa * wv.z; acc0[3] += xa * wv.w;
            acc1[0] += xb * wv.x; acc1[1] += xb * wv.y;
            acc1[2] += xb * wv.z; acc1[3] += xb * wv.w;
        }
    }

    float* yp = Yp + ((long)ks * (EE * BB) + (long)e * BB + r0) * OUT + c;
    *(float4*)yp         = make_float4(acc0[0], acc0[1], acc0[2], acc0[3]);
    *(float4*)(yp + OUT) = make_float4(acc1[0], acc1[1], acc1[2], acc1[3]);
}

// Reduce KS partials + bias, then LayerNorm + mish.
template<int KS, bool HAS_BIAS>
__global__ __launch_bounds__(256)
void k_lnact(const float* __restrict__ Yp, const float* __restrict__ bias,
             const float* __restrict__ g, const float* __restrict__ be,
             float* __restrict__ Yo) {
    __shared__ float redS[4], redQ[4];
    int row = blockIdx.x, t = threadIdx.x;
    int e = row >> 6;

    float v[2];
#pragma unroll
    for (int j = 0; j < 2; j++) {
        int cj = t + j * 256;
        float s = HAS_BIAS ? bias[(long)e * HH + cj] : 0.f;
#pragma unroll
        for (int ks = 0; ks < KS; ks++)
            s += Yp[((long)ks * (EE * BB) + row) * HH + cj];
        v[j] = s;
    }
    float s = v[0] + v[1];
    float q = v[0] * v[0] + v[1] * v[1];
    for (int off = 32; off > 0; off >>= 1) {
        s += __shfl_xor(s, off);
        q += __shfl_xor(q, off);
    }
    int wave = t >> 6, lane = t & 63;
    if (lane == 0) { redS[wave] = s; redQ[wave] = q; }
    __syncthreads();
    float S = redS[0] + redS[1] + redS[2] + redS[3];
    float Q = redQ[0] + redQ[1] + redQ[2] + redQ[3];
    float mean = S * (1.f / HH);
    float var = Q * (1.f / HH) - mean * mean;
    float rstd = rsqrtf(var + LN_EPS);

#pragma unroll
    for (int j = 0; j < 2; j++) {
        int cj = t + j * 256;
        float gg = g[(long)e * HH + cj], bb = be[(long)e * HH + cj];
        Yo[(long)row * HH + cj] = mishf((v[j] - mean) * rstd * gg + bb);
    }
}

// Reduce gemm3 partials + bias, scatter to eout[b][e][DZ].
template<int KS>
__global__ __launch_bounds__(256)
void k_fin3(const float* __restrict__ p3, const float* __restrict__ b3,
            float* __restrict__ eout) {
    int t = threadIdx.x;
    int row = blockIdx.x * 2 + (t >> 7);
    int c = t & 127;
    int e = row >> 6, b = row & 63;
    float s = b3[(long)e * DZ + c];
#pragma unroll
    for (int ks = 0; ks < KS; ks++)
        s += p3[((long)ks * (EE * BB) + row) * DZ + c];
    eout[((long)b * EE + e) * DZ + c] = s;
}

// ---------------- K5: combine softmax over E + mix ----------------
__global__ __launch_bounds__(256)
void k_combine(const float* __restrict__ w, const float* __restrict__ eout,
               float* __restrict__ out) {
    __shared__ float comb[64][EE];
    __shared__ float eo[EE * DZ];
    int b = blockIdx.y, n0 = blockIdx.x * 64, t = threadIdx.x;

    for (int i = t; i < EE * DZ; i += 256) eo[i] = eout[(long)b * EE * DZ + i];

    int tok = t >> 2, sub = t & 3;
    const float4 wv = *(const float4*)(w + ((long)b * NN + n0 + tok) * EE + sub * 4);
    float mx = fmaxf(fmaxf(wv.x, wv.y), fmaxf(wv.z, wv.w));
    mx = fmaxf(mx, __shfl_xor(mx, 1, 4));
    mx = fmaxf(mx, __shfl_xor(mx, 2, 4));
    float e0 = __expf(wv.x - mx), e1 = __expf(wv.y - mx);
    float e2 = __expf(wv.z - mx), e3 = __expf(wv.w - mx);
    float s = e0 + e1 + e2 + e3;
    s += __shfl_xor(s, 1, 4);
    s += __shfl_xor(s, 2, 4);
    float rs = 1.f / s;
    comb[tok][sub * 4 + 0] = e0 * rs;
    comb[tok][sub * 4 + 1] = e1 * rs;
    comb[tok][sub * 4 + 2] = e2 * rs;
    comb[tok][sub * 4 + 3] = e3 * rs;
    __syncthreads();

    for (int i = t; i < 64 * DZ; i += 256) {
        int tk = i >> 7, c = i & 127;
        float acc = 0.f;
#pragma unroll
        for (int e = 0; e < EE; e++) acc += comb[tk][e] * eo[e * DZ + c];
        out[((long)b * NN + n0 + tk) * DZ + c] = acc;
    }
}

extern "C" void kernel_launch(void* const* d_in, const int* in_sizes, int n_in,
                              void* d_out, int out_size, void* d_ws, size_t ws_size,
                              hipStream_t stream) {
    const float* z   = (const float*)d_in[0];
    const float* a   = (const float*)d_in[1];
    const float* phi = (const float*)d_in[2];
    const float* W1  = (const float*)d_in[3];
    const float* b1  = (const float*)d_in[4];
    const float* g1  = (const float*)d_in[5];
    const float* be1 = (const float*)d_in[6];
    const float* W2  = (const float*)d_in[7];
    const float* b2  = (const float*)d_in[8];
    const float* g2  = (const float*)d_in[9];
    const float* be2 = (const float*)d_in[10];
    const float* W3  = (const float*)d_in[11];
    const float* b3  = (const float*)d_in[12];
    float* out = (float*)d_out;

    char* p = (char*)d_ws;
    float* w    = (float*)p; p += (size_t)BB * NN * EE * 4;          // 8.39 MB
    float* gmax = (float*)p; p += (size_t)BB * EE * 4;
    float* grcp = (float*)p; p += (size_t)BB * EE * 4;
    float* lmax = (float*)p; p += (size_t)BB * 4 * EE * 4;
    float* lsum = (float*)p; p += (size_t)BB * 4 * EE * 4;
    float* xin  = (float*)p; p += (size_t)BB * EE * DD * 4;          // 786 KB
    unsigned short* php = (unsigned short*)p; p += 6 * 64 * 8 * 2;   // 6 KB
    unsigned short* plp = (unsigned short*)p; p += 6 * 64 * 8 * 2;   // 6 KB
    // REGION: time-shared between pxin (16*786KB, phase A) and
    // gemm partials + h1 + eout (11 MB, phase B)
    char* region = p;
    float* pxin = (float*)region;                                    // 12.6 MB
    float* part = (float*)region;                                    // 8.39 MB
    float* h1   = (float*)(region + (size_t)4 * EE * BB * HH * 4);   // 2.1 MB
    float* h2   = h1;
    float* eout = (float*)(region + (size_t)4 * EE * BB * HH * 4
                                  + (size_t)EE * BB * HH * 4);       // 524 KB
    size_t region_off = (size_t)(region - (char*)d_ws);
    size_t need_full = region_off + (size_t)16 * EE * BB * DD * 4;
    bool full = ws_size >= need_full;

    k_phipack<<<12, 256, 0, stream>>>(phi, php, plp);
    k_weights<<<BB * NN / 64, 256, 0, stream>>>(z, a, php, plp, w);
    k_stats1<<<dim3(4, BB), 256, 0, stream>>>(w, lmax, lsum);

    if (full) {
        k_xin2<<<dim3(16, BB), 256, 0, stream>>>(z, a, w, lmax, lsum, pxin);
        k_xinred<<<EE * BB * DD / 256, 256, 0, stream>>>(pxin, xin);
    } else {
        k_stats2<<<4, 256, 0, stream>>>(lmax, lsum, gmax, grcp);
        hipMemsetAsync(xin, 0, (size_t)BB * EE * DD * 4, stream);
        k_xin_scalar<<<dim3(NN / 128, BB), 192, 0, stream>>>(z, a, w, gmax, grcp, xin);
    }

    // layer 1: 192 -> 512, split-K 2
    k_gemm<DD, HH, 96, false>
        <<<dim3(HH / 32, 2, EE), 256, 0, stream>>>(xin, W1, nullptr, part);
    k_lnact<2, true><<<EE * BB, 256, 0, stream>>>(part, b1, g1, be1, h1);

    // layer 2: 512 -> 512, split-K 4
    k_gemm<HH, HH, 128, false>
        <<<dim3(HH / 32, 4, EE), 256, 0, stream>>>(h1, W2, nullptr, part);
    k_lnact<4, true><<<EE * BB, 256, 0, stream>>>(part, b2, g2, be2, h2);

    // layer 3: 512 -> 128, split-K 8
    k_gemm<HH, DZ, 64, false>
        <<<dim3(DZ / 32, 8, EE), 256, 0, stream>>>(h2, W3, nullptr, part);
    k_fin3<8><<<EE * BB / 2, 256, 0, stream>>>(part, b3, eout);

    k_combine<<<dim3(NN / 64, BB), 256, 0, stream>>>(w, eout, out);
}

// Round 10
// 132.942 us; speedup vs baseline: 1.0190x; 1.0190x over previous
//
#include <hip/hip_runtime.h>
#include <math.h>

#define BB 64
#define NN 2048
#define DZ 128
#define DA 64
#define DD 192
#define EE 16
#define HH 512
#define LN_EPS 1e-5f

typedef __attribute__((ext_vector_type(8))) short short8;
typedef __attribute__((ext_vector_type(4))) float f32x4;

__device__ __forceinline__ float mishf(float x) {
    float sp = (x > 20.f) ? x : log1pf(__expf(x));
    return x * tanhf(sp);
}

__device__ __forceinline__ unsigned short bf16_rne(float f) {
    unsigned u = __float_as_uint(f);
    return (unsigned short)((u + 0x7FFFu + ((u >> 16) & 1u)) >> 16);
}
__device__ __forceinline__ float bf16f(unsigned short h) {
    return __uint_as_float(((unsigned)h) << 16);
}

// async global->LDS, 16B per lane: writes lds_base + lane*16, reads per-lane gptr
__device__ __forceinline__ void gload_lds16(const float* g, float* l) {
    __builtin_amdgcn_global_load_lds(
        (const __attribute__((address_space(1))) void*)g,
        (__attribute__((address_space(3))) void*)l, 16, 0, 0);
}

// ---------------- phi pre-pack: per-lane MFMA B-fragments, bf16 hi/lo ----------------
// layout: [kk<6][lane<64][j<8];  lane: e = lane&15 (col), g = lane>>4; k = kk*32+g*8+j
__global__ __launch_bounds__(256)
void k_phipack(const float* __restrict__ phi, unsigned short* __restrict__ ph,
               unsigned short* __restrict__ pl) {
    int idx = blockIdx.x * 256 + threadIdx.x;      // < 3072
    if (idx >= 6 * 64 * 8) return;
    int j = idx & 7, lane = (idx >> 3) & 63, kk = idx >> 9;
    int e = lane & 15, g = lane >> 4;
    int d = kk * 32 + g * 8 + j;
    float f = phi[d * EE + e];
    unsigned short h = bf16_rne(f);
    ph[idx] = h;
    pl[idx] = bf16_rne(f - bf16f(h));
}

// ---------------- K1: weights = x @ phi via split-bf16 MFMA ----------------
__global__ __launch_bounds__(256)
void k_weights(const float* __restrict__ z, const float* __restrict__ a,
               const unsigned short* __restrict__ php,
               const unsigned short* __restrict__ plp,
               float* __restrict__ w) {
    int t = threadIdx.x;
    int wv = t >> 6, l = t & 63;
    long tokbase = ((long)blockIdx.x * 4 + wv) * 16;
    long tokA = tokbase + (l & 15);
    int g = l >> 4;

    short8 bh[6], bl[6], ah[6], al[6];
#pragma unroll
    for (int kk = 0; kk < 6; kk++) {
        bh[kk] = *(const short8*)(php + kk * 512 + l * 8);
        bl[kk] = *(const short8*)(plp + kk * 512 + l * 8);
    }
#pragma unroll
    for (int kk = 0; kk < 6; kk++) {
        int d0 = kk * 32 + g * 8;                  // 8-elem chunk never straddles z/a
        const float* src = (d0 < DZ) ? (z + tokA * DZ + d0)
                                     : (a + tokA * DA + (d0 - DZ));
        float4 v0 = ((const float4*)src)[0];
        float4 v1 = ((const float4*)src)[1];
        float f[8] = {v0.x, v0.y, v0.z, v0.w, v1.x, v1.y, v1.z, v1.w};
#pragma unroll
        for (int j = 0; j < 8; j++) {
            unsigned short h = bf16_rne(f[j]);
            ah[kk][j] = (short)h;
            al[kk][j] = (short)bf16_rne(f[j] - bf16f(h));
        }
    }

    f32x4 acc = {0.f, 0.f, 0.f, 0.f};
#pragma unroll
    for (int kk = 0; kk < 6; kk++)
        acc = __builtin_amdgcn_mfma_f32_16x16x32_bf16(ah[kk], bh[kk], acc, 0, 0, 0);
#pragma unroll
    for (int kk = 0; kk < 6; kk++)
        acc = __builtin_amdgcn_mfma_f32_16x16x32_bf16(al[kk], bh[kk], acc, 0, 0, 0);
#pragma unroll
    for (int kk = 0; kk < 6; kk++)
        acc = __builtin_amdgcn_mfma_f32_16x16x32_bf16(ah[kk], bl[kk], acc, 0, 0, 0);

    int e = l & 15;                                 // D: col = lane&15
#pragma unroll
    for (int r = 0; r < 4; r++) {
        long row = tokbase + g * 4 + r;             // D: row = (lane>>4)*4 + r
        w[row * EE + e] = acc[r];
    }
}

// ---------------- K2: softmax stats over n, chunked ----------------
#define RSTR 17
__global__ __launch_bounds__(256)
void k_stats1(const float* __restrict__ w, float* __restrict__ lmax,
              float* __restrict__ lsum) {
    __shared__ float red[256 * RSTR];
    int b = blockIdx.y, c = blockIdx.x, t = threadIdx.x;
    const float* wb = w + ((long)b * NN + c * 512) * EE;

    float m[EE];
#pragma unroll
    for (int e = 0; e < EE; e++) m[e] = -1e30f;
    for (int k = 0; k < 2; k++) {
        const float4* row = (const float4*)(wb + ((long)(k * 256 + t)) * EE);
#pragma unroll
        for (int q = 0; q < 4; q++) {
            float4 v = row[q];
            m[q * 4 + 0] = fmaxf(m[q * 4 + 0], v.x);
            m[q * 4 + 1] = fmaxf(m[q * 4 + 1], v.y);
            m[q * 4 + 2] = fmaxf(m[q * 4 + 2], v.z);
            m[q * 4 + 3] = fmaxf(m[q * 4 + 3], v.w);
        }
    }
#pragma unroll
    for (int e = 0; e < EE; e++) red[t * RSTR + e] = m[e];
    __syncthreads();
    for (int s = 128; s > 0; s >>= 1) {
        if (t < s) {
#pragma unroll
            for (int e = 0; e < EE; e++)
                red[t * RSTR + e] = fmaxf(red[t * RSTR + e], red[(t + s) * RSTR + e]);
        }
        __syncthreads();
    }
    float mg[EE];
#pragma unroll
    for (int e = 0; e < EE; e++) mg[e] = red[e];
    __syncthreads();

    float s_[EE];
#pragma unroll
    for (int e = 0; e < EE; e++) s_[e] = 0.f;
    for (int k = 0; k < 2; k++) {
        const float4* row = (const float4*)(wb + ((long)(k * 256 + t)) * EE);
#pragma unroll
        for (int q = 0; q < 4; q++) {
            float4 v = row[q];
            s_[q * 4 + 0] += __expf(v.x - mg[q * 4 + 0]);
            s_[q * 4 + 1] += __expf(v.y - mg[q * 4 + 1]);
            s_[q * 4 + 2] += __expf(v.z - mg[q * 4 + 2]);
            s_[q * 4 + 3] += __expf(v.w - mg[q * 4 + 3]);
        }
    }
#pragma unroll
    for (int e = 0; e < EE; e++) red[t * RSTR + e] = s_[e];
    __syncthreads();
    for (int s = 128; s > 0; s >>= 1) {
        if (t < s) {
#pragma unroll
            for (int e = 0; e < EE; e++)
                red[t * RSTR + e] += red[(t + s) * RSTR + e];
        }
        __syncthreads();
    }
    if (t < EE) {
        lmax[((long)b * 4 + c) * EE + t] = mg[t];
        lsum[((long)b * 4 + c) * EE + t] = red[t];
    }
}

__global__ __launch_bounds__(256)
void k_stats2(const float* __restrict__ lmax, const float* __restrict__ lsum,
              float* __restrict__ gmax, float* __restrict__ grcp) {
    int idx = blockIdx.x * 256 + threadIdx.x;
    if (idx >= BB * EE) return;
    int b = idx >> 4, e = idx & 15;
    float gm = -1e30f;
#pragma unroll
    for (int c = 0; c < 4; c++)
        gm = fmaxf(gm, lmax[((long)b * 4 + c) * EE + e]);
    float Z = 0.f;
#pragma unroll
    for (int c = 0; c < 4; c++)
        Z += __expf(lmax[((long)b * 4 + c) * EE + e] - gm) * lsum[((long)b * 4 + c) * EE + e];
    gmax[idx] = gm;
    grcp[idx] = 1.f / Z;
}

// ---------------- K3: xin = disp^T @ x via split-bf16 MFMA, LDS-staged ----------------
// v3: SINGLE-buffered 32-token chunks -> 27 KB LDS -> ~6 blocks/CU. Cross-block TLP
// hides the per-chunk vmcnt(0) drain (m114). Padded segments keep LDS reads <=2-way.
#define SEGZ 260
#define SEGA 260
#define SEGW 272
__global__ __launch_bounds__(256)
void k_xin2(const float* __restrict__ z, const float* __restrict__ a,
            const float* __restrict__ w, const float* __restrict__ lmax,
            const float* __restrict__ lsum, float* __restrict__ pxin) {
    __shared__ float zs[16 * SEGZ];   // 16.6 KB
    __shared__ float as_[8 * SEGA];   //  8.3 KB
    __shared__ float ws_[2 * SEGW];   //  2.2 KB
    int kq = blockIdx.x, b = blockIdx.y;
    int t = threadIdx.x, wv = t >> 6, l = t & 63;
    int g = l >> 4, c = l & 15;

    // inline softmax-stat combine for e = c (replaces k_stats2)
    float gm = -1e30f;
#pragma unroll
    for (int cc = 0; cc < 4; cc++)
        gm = fmaxf(gm, lmax[((long)b * 4 + cc) * EE + c]);
    float Zs = 0.f;
#pragma unroll
    for (int cc = 0; cc < 4; cc++)
        Zs += __expf(lmax[((long)b * 4 + cc) * EE + c] - gm)
            * lsum[((long)b * 4 + cc) * EE + c];
    float gr = 1.f / Zs;

    const float* zb = z + ((long)b * NN + (long)kq * 128) * DZ;  // 64 KB contiguous
    const float* ab = a + ((long)b * NN + (long)kq * 128) * DA;  // 32 KB contiguous
    const float* wb = w + ((long)b * NN + (long)kq * 128) * EE;  //  8 KB contiguous

    auto stage = [&](int kk) {
#pragma unroll
        for (int s = 0; s < 4; s++) {
            int seg = wv * 4 + s;
            gload_lds16(zb + kk * 4096 + seg * 256 + l * 4, &zs[seg * SEGZ]);
        }
#pragma unroll
        for (int s = 0; s < 2; s++) {
            int seg = wv * 2 + s;
            gload_lds16(ab + kk * 2048 + seg * 256 + l * 4, &as_[seg * SEGA]);
        }
        if (wv < 2)
            gload_lds16(wb + kk * 512 + wv * 256 + l * 4, &ws_[wv * SEGW]);
    };

    f32x4 acc0 = {0.f, 0.f, 0.f, 0.f};
    f32x4 acc1 = {0.f, 0.f, 0.f, 0.f};
    f32x4 acc2 = {0.f, 0.f, 0.f, 0.f};

#pragma unroll
    for (int kk = 0; kk < 4; kk++) {
        stage(kk);
        __syncthreads();   // drains vmcnt -> staged chunk visible

        // A: dispatch fragment, row = e = c, k-slot n = g*8+j
        short8 ad;
#pragma unroll
        for (int j = 0; j < 8; j++) {
            int n = g * 8 + j;
            float wvv = ws_[(n >> 4) * SEGW + (n & 15) * 16 + c];
            ad[j] = (short)bf16_rne(__expf(wvv - gm) * gr);
        }
        // B: three d-tiles per wave, col = d = (wv*3+i)*16 + c, split hi/lo
#pragma unroll
        for (int i = 0; i < 3; i++) {
            int d = (wv * 3 + i) * 16 + c;
            short8 xh_, xl_;
#pragma unroll
            for (int j = 0; j < 8; j++) {
                int n = g * 8 + j;
                float f = (d < DZ)
                    ? zs[(n >> 1) * SEGZ + (n & 1) * 128 + d]
                    : as_[(n >> 2) * SEGA + (n & 3) * 64 + (d - DZ)];
                unsigned short h = bf16_rne(f);
                xh_[j] = (short)h;
                xl_[j] = (short)bf16_rne(f - bf16f(h));
            }
            if (i == 0) {
                acc0 = __builtin_amdgcn_mfma_f32_16x16x32_bf16(ad, xh_, acc0, 0, 0, 0);
                acc0 = __builtin_amdgcn_mfma_f32_16x16x32_bf16(ad, xl_, acc0, 0, 0, 0);
            } else if (i == 1) {
                acc1 = __builtin_amdgcn_mfma_f32_16x16x32_bf16(ad, xh_, acc1, 0, 0, 0);
                acc1 = __builtin_amdgcn_mfma_f32_16x16x32_bf16(ad, xl_, acc1, 0, 0, 0);
            } else {
                acc2 = __builtin_amdgcn_mfma_f32_16x16x32_bf16(ad, xh_, acc2, 0, 0, 0);
                acc2 = __builtin_amdgcn_mfma_f32_16x16x32_bf16(ad, xl_, acc2, 0, 0, 0);
            }
        }
        __syncthreads();   // all reads done before next chunk overwrites
    }

    // D: col = d-in-tile = c, row = e = g*4 + r.  pxin[kq][e*BB+b][DD]
    float* pb = pxin + (long)kq * (EE * BB * DD) + (long)b * DD;
#pragma unroll
    for (int r = 0; r < 4; r++) {
        int e = g * 4 + r;
        float* pr = pb + (long)e * (BB * DD);
        pr[(wv * 3 + 0) * 16 + c] = acc0[r];
        pr[(wv * 3 + 1) * 16 + c] = acc1[r];
        pr[(wv * 3 + 2) * 16 + c] = acc2[r];
    }
}

// ---------------- K3 fallback (atomic, small-ws) ----------------
__global__ __launch_bounds__(192)
void k_xin_scalar(const float* __restrict__ z, const float* __restrict__ a,
                  const float* __restrict__ w, const float* __restrict__ gmax,
                  const float* __restrict__ grcp, float* __restrict__ dst) {
    __shared__ float disp[128 * EE];
    int b = blockIdx.y, chunk = blockIdx.x, t = threadIdx.x;

    const float* wrow = w + ((long)b * NN + (long)chunk * 128) * EE;
    for (int i = t; i < 128 * EE; i += 192) {
        int e = i & 15;
        disp[i] = __expf(wrow[i] - gmax[b * EE + e]) * grcp[b * EE + e];
    }
    __syncthreads();

    const float* xp;
    int stride;
    if (t < DZ) { xp = z + ((long)b * NN + (long)chunk * 128) * DZ + t; stride = DZ; }
    else        { xp = a + ((long)b * NN + (long)chunk * 128) * DA + (t - DZ); stride = DA; }

    float acc[EE];
#pragma unroll
    for (int e = 0; e < EE; e++) acc[e] = 0.f;

    for (int n = 0; n < 128; n++) {
        float xv = xp[(long)n * stride];
        const float4* dp = (const float4*)(disp + n * EE);
#pragma unroll
        for (int q = 0; q < 4; q++) {
            float4 p = dp[q];
            acc[q * 4 + 0] += p.x * xv;
            acc[q * 4 + 1] += p.y * xv;
            acc[q * 4 + 2] += p.z * xv;
            acc[q * 4 + 3] += p.w * xv;
        }
    }
#pragma unroll
    for (int e = 0; e < EE; e++)
        atomicAdd(&dst[((long)e * BB + b) * DD + t], acc[e]);
}

// reduce 16 partials -> xin[e][b][d]
__global__ __launch_bounds__(256)
void k_xinred(const float* __restrict__ xinp, float* __restrict__ xin) {
    long i = (long)blockIdx.x * 256 + threadIdx.x;   // < EE*BB*DD = 196608
    float s = 0.f;
#pragma unroll
    for (int c = 0; c < 16; c++)
        s += xinp[(long)c * (EE * BB * DD) + i];
    xin[i] = s;
}

// ---------------- Split-K per-expert GEMM ----------------
template<int K, int OUT, int KSLICE, bool ADD_BIAS>
__global__ __launch_bounds__(256)
void k_gemm(const float* __restrict__ X, const float* __restrict__ W,
            const float* __restrict__ bias, float* __restrict__ Yp) {
    constexpr int SP = KSLICE + 4;
    constexpr int K4 = KSLICE / 4;
    __shared__ float xs[64 * SP];

    int cb = blockIdx.x, ks = blockIdx.y, e = blockIdx.z;
    int t = threadIdx.x;
    int k0 = ks * KSLICE;

    for (int i = t; i < 64 * K4; i += 256) {
        int r = i / K4, k4 = i % K4;
        *(float4*)&xs[r * SP + k4 * 4] =
            *(const float4*)(X + ((long)e * BB + r) * K + k0 + k4 * 4);
    }
    __syncthreads();

    int c = cb * 32 + (t & 7) * 4;
    int r0 = (t >> 3) * 2;
    const float* Wp = W + ((long)e * K + k0) * OUT + c;

    float acc0[4], acc1[4];
#pragma unroll
    for (int j = 0; j < 4; j++) {
        float bv = ADD_BIAS ? bias[(long)e * OUT + c + j] : 0.f;
        acc0[j] = bv;
        acc1[j] = bv;
    }

#pragma unroll 4
    for (int k4 = 0; k4 < K4; k4++) {
        float4 x0 = *(const float4*)&xs[r0 * SP + k4 * 4];
        float4 x1 = *(const float4*)&xs[(r0 + 1) * SP + k4 * 4];
        const float* xp0 = &x0.x;
        const float* xp1 = &x1.x;
#pragma unroll
        for (int j = 0; j < 4; j++) {
            float4 wv = *(const float4*)(Wp + (long)(k4 * 4 + j) * OUT);
            float xa = xp0[j], xb = xp1[j];
            acc0[0] += xa * wv.x; acc0[1] += xa * wv.y;
            acc0[2] += xa * wv.z; acc0[3] += xa * wv.w;
            acc1[0] += xb * wv.x; acc1[1] += xb * wv.y;
            acc1[2] += xb * wv.z; acc1[3] += xb * wv.w;
        }
    }

    float* yp = Yp + ((long)ks * (EE * BB) + (long)e * BB + r0) * OUT + c;
    *(float4*)yp         = make_float4(acc0[0], acc0[1], acc0[2], acc0[3]);
    *(float4*)(yp + OUT) = make_float4(acc1[0], acc1[1], acc1[2], acc1[3]);
}

// Reduce KS partials + bias, then LayerNorm + mish.
template<int KS, bool HAS_BIAS>
__global__ __launch_bounds__(256)
void k_lnact(const float* __restrict__ Yp, const float* __restrict__ bias,
             const float* __restrict__ g, const float* __restrict__ be,
             float* __restrict__ Yo) {
    __shared__ float redS[4], redQ[4];
    int row = blockIdx.x, t = threadIdx.x;
    int e = row >> 6;

    float v[2];
#pragma unroll
    for (int j = 0; j < 2; j++) {
        int cj = t + j * 256;
        float s = HAS_BIAS ? bias[(long)e * HH + cj] : 0.f;
#pragma unroll
        for (int ks = 0; ks < KS; ks++)
            s += Yp[((long)ks * (EE * BB) + row) * HH + cj];
        v[j] = s;
    }
    float s = v[0] + v[1];
    float q = v[0] * v[0] + v[1] * v[1];
    for (int off = 32; off > 0; off >>= 1) {
        s += __shfl_xor(s, off);
        q += __shfl_xor(q, off);
    }
    int wave = t >> 6, lane = t & 63;
    if (lane == 0) { redS[wave] = s; redQ[wave] = q; }
    __syncthreads();
    float S = redS[0] + redS[1] + redS[2] + redS[3];
    float Q = redQ[0] + redQ[1] + redQ[2] + redQ[3];
    float mean = S * (1.f / HH);
    float var = Q * (1.f / HH) - mean * mean;
    float rstd = rsqrtf(var + LN_EPS);

#pragma unroll
    for (int j = 0; j < 2; j++) {
        int cj = t + j * 256;
        float gg = g[(long)e * HH + cj], bb = be[(long)e * HH + cj];
        Yo[(long)row * HH + cj] = mishf((v[j] - mean) * rstd * gg + bb);
    }
}

// Reduce gemm3 partials + bias, scatter to eout[b][e][DZ].
template<int KS>
__global__ __launch_bounds__(256)
void k_fin3(const float* __restrict__ p3, const float* __restrict__ b3,
            float* __restrict__ eout) {
    int t = threadIdx.x;
    int row = blockIdx.x * 2 + (t >> 7);
    int c = t & 127;
    int e = row >> 6, b = row & 63;
    float s = b3[(long)e * DZ + c];
#pragma unroll
    for (int ks = 0; ks < KS; ks++)
        s += p3[((long)ks * (EE * BB) + row) * DZ + c];
    eout[((long)b * EE + e) * DZ + c] = s;
}

// ---------------- K5: combine softmax over E + mix ----------------
__global__ __launch_bounds__(256)
void k_combine(const float* __restrict__ w, const float* __restrict__ eout,
               float* __restrict__ out) {
    __shared__ float comb[64][EE];
    __shared__ float eo[EE * DZ];
    int b = blockIdx.y, n0 = blockIdx.x * 64, t = threadIdx.x;

    for (int i = t; i < EE * DZ; i += 256) eo[i] = eout[(long)b * EE * DZ + i];

    int tok = t >> 2, sub = t & 3;
    const float4 wv = *(const float4*)(w + ((long)b * NN + n0 + tok) * EE + sub * 4);
    float mx = fmaxf(fmaxf(wv.x, wv.y), fmaxf(wv.z, wv.w));
    mx = fmaxf(mx, __shfl_xor(mx, 1, 4));
    mx = fmaxf(mx, __shfl_xor(mx, 2, 4));
    float e0 = __expf(wv.x - mx), e1 = __expf(wv.y - mx);
    float e2 = __expf(wv.z - mx), e3 = __expf(wv.w - mx);
    float s = e0 + e1 + e2 + e3;
    s += __shfl_xor(s, 1, 4);
    s += __shfl_xor(s, 2, 4);
    float rs = 1.f / s;
    comb[tok][sub * 4 + 0] = e0 * rs;
    comb[tok][sub * 4 + 1] = e1 * rs;
    comb[tok][sub * 4 + 2] = e2 * rs;
    comb[tok][sub * 4 + 3] = e3 * rs;
    __syncthreads();

    for (int i = t; i < 64 * DZ; i += 256) {
        int tk = i >> 7, c = i & 127;
        float acc = 0.f;
#pragma unroll
        for (int e = 0; e < EE; e++) acc += comb[tk][e] * eo[e * DZ + c];
        out[((long)b * NN + n0 + tk) * DZ + c] = acc;
    }
}

extern "C" void kernel_launch(void* const* d_in, const int* in_sizes, int n_in,
                              void* d_out, int out_size, void* d_ws, size_t ws_size,
                              hipStream_t stream) {
    const float* z   = (const float*)d_in[0];
    const float* a   = (const float*)d_in[1];
    const float* phi = (const float*)d_in[2];
    const float* W1  = (const float*)d_in[3];
    const float* b1  = (const float*)d_in[4];
    const float* g1  = (const float*)d_in[5];
    const float* be1 = (const float*)d_in[6];
    const float* W2  = (const float*)d_in[7];
    const float* b2  = (const float*)d_in[8];
    const float* g2  = (const float*)d_in[9];
    const float* be2 = (const float*)d_in[10];
    const float* W3  = (const float*)d_in[11];
    const float* b3  = (const float*)d_in[12];
    float* out = (float*)d_out;

    char* p = (char*)d_ws;
    float* w    = (float*)p; p += (size_t)BB * NN * EE * 4;          // 8.39 MB
    float* gmax = (float*)p; p += (size_t)BB * EE * 4;
    float* grcp = (float*)p; p += (size_t)BB * EE * 4;
    float* lmax = (float*)p; p += (size_t)BB * 4 * EE * 4;
    float* lsum = (float*)p; p += (size_t)BB * 4 * EE * 4;
    float* xin  = (float*)p; p += (size_t)BB * EE * DD * 4;          // 786 KB
    unsigned short* php = (unsigned short*)p; p += 6 * 64 * 8 * 2;   // 6 KB
    unsigned short* plp = (unsigned short*)p; p += 6 * 64 * 8 * 2;   // 6 KB
    // REGION: time-shared between pxin (16*786KB, phase A) and
    // gemm partials + h1 + eout (11 MB, phase B)
    char* region = p;
    float* pxin = (float*)region;                                    // 12.6 MB
    float* part = (float*)region;                                    // 8.39 MB
    float* h1   = (float*)(region + (size_t)4 * EE * BB * HH * 4);   // 2.1 MB
    float* h2   = h1;
    float* eout = (float*)(region + (size_t)4 * EE * BB * HH * 4
                                  + (size_t)EE * BB * HH * 4);       // 524 KB
    size_t region_off = (size_t)(region - (char*)d_ws);
    size_t need_full = region_off + (size_t)16 * EE * BB * DD * 4;
    bool full = ws_size >= need_full;

    k_phipack<<<12, 256, 0, stream>>>(phi, php, plp);
    k_weights<<<BB * NN / 64, 256, 0, stream>>>(z, a, php, plp, w);
    k_stats1<<<dim3(4, BB), 256, 0, stream>>>(w, lmax, lsum);

    if (full) {
        k_xin2<<<dim3(16, BB), 256, 0, stream>>>(z, a, w, lmax, lsum, pxin);
        k_xinred<<<EE * BB * DD / 256, 256, 0, stream>>>(pxin, xin);
    } else {
        k_stats2<<<4, 256, 0, stream>>>(lmax, lsum, gmax, grcp);
        hipMemsetAsync(xin, 0, (size_t)BB * EE * DD * 4, stream);
        k_xin_scalar<<<dim3(NN / 128, BB), 192, 0, stream>>>(z, a, w, gmax, grcp, xin);
    }

    // layer 1: 192 -> 512, split-K 2
    k_gemm<DD, HH, 96, false>
        <<<dim3(HH / 32, 2, EE), 256, 0, stream>>>(xin, W1, nullptr, part);
    k_lnact<2, true><<<EE * BB, 256, 0, stream>>>(part, b1, g1, be1, h1);

    // layer 2: 512 -> 512, split-K 4
    k_gemm<HH, HH, 128, false>
        <<<dim3(HH / 32, 4, EE), 256, 0, stream>>>(h1, W2, nullptr, part);
    k_lnact<4, true><<<EE * BB, 256, 0, stream>>>(part, b2, g2, be2, h2);

    // layer 3: 512 -> 128, split-K 8
    k_gemm<HH, DZ, 64, false>
        <<<dim3(DZ / 32, 8, EE), 256, 0, stream>>>(h2, W3, nullptr, part);
    k_fin3<8><<<EE * BB / 2, 256, 0, stream>>>(part, b3, eout);

    k_combine<<<dim3(NN / 64, BB), 256, 0, stream>>>(w, eout, out);
}

// Round 11
// 127.567 us; speedup vs baseline: 1.0620x; 1.0421x over previous
//
#include <hip/hip_runtime.h>
#include <math.h>

#define BB 64
#define NN 2048
#define DZ 128
#define DA 64
#define DD 192
#define EE 16
#define HH 512
#define LN_EPS 1e-5f
#define NCH 64            // 32-token chunks per b

typedef __attribute__((ext_vector_type(8))) short short8;
typedef __attribute__((ext_vector_type(4))) float f32x4;

__device__ __forceinline__ float mishf(float x) {
    float sp = (x > 20.f) ? x : log1pf(__expf(x));
    return x * tanhf(sp);
}

__device__ __forceinline__ unsigned short bf16_rne(float f) {
    unsigned u = __float_as_uint(f);
    return (unsigned short)((u + 0x7FFFu + ((u >> 16) & 1u)) >> 16);
}
__device__ __forceinline__ float bf16f(unsigned short h) {
    return __uint_as_float(((unsigned)h) << 16);
}

// ---------------- phi pre-pack: per-lane MFMA B-fragments, bf16 hi/lo ----------------
// layout: [kk<6][lane<64][j<8];  lane: e = lane&15 (col), g = lane>>4; k = kk*32+g*8+j
__global__ __launch_bounds__(256)
void k_phipack(const float* __restrict__ phi, unsigned short* __restrict__ ph,
               unsigned short* __restrict__ pl) {
    int idx = blockIdx.x * 256 + threadIdx.x;
    if (idx >= 6 * 64 * 8) return;
    int j = idx & 7, lane = (idx >> 3) & 63, kk = idx >> 9;
    int e = lane & 15, g = lane >> 4;
    int d = kk * 32 + g * 8 + j;
    float f = phi[d * EE + e];
    unsigned short h = bf16_rne(f);
    ph[idx] = h;
    pl[idx] = bf16_rne(f - bf16f(h));
}

// ---------------- K1 (fused): w = x@phi  AND  U-partial = exp(w)^T @ x ----------------
// Block = (32-token chunk, b), 4 waves, 2 barriers TOTAL per block (no per-chunk drain).
// LDS: xhl[4 region][32 n][49] u32 (hi<<16|lo bf16)  + wexp[32][17] f32  = 27.3 KB.
__global__ __launch_bounds__(256)
void k_wxin(const float* __restrict__ z, const float* __restrict__ a,
            const unsigned short* __restrict__ php,
            const unsigned short* __restrict__ plp,
            float* __restrict__ w, float* __restrict__ pxin,
            float* __restrict__ pZ) {
    __shared__ unsigned int xhl[4 * 32 * 49];   // 25.1 KB
    __shared__ float wexp[32 * 17];             //  2.2 KB
    int ch = blockIdx.x, b = blockIdx.y;
    int t = threadIdx.x, wv = t >> 6, l = t & 63;
    int g = l >> 4, c = l & 15;
    long tok0 = (long)b * NN + (long)ch * 32;

    // ---- phase 0: cooperative x load -> LDS as packed hi/lo bf16
    {
        const float4* zp = (const float4*)(z + tok0 * DZ);
        const float4* ap = (const float4*)(a + tok0 * DA);
#pragma unroll
        for (int k = 0; k < 6; k++) {
            int f = t + k * 256;                 // < 1536
            int tok = f / 48, q = f - tok * 48;
            float4 v = (q < 32) ? zp[tok * 32 + q] : ap[tok * 16 + (q - 32)];
            int reg = q / 12;                    // d=4q, region=d/48
            int dq = q * 4 - reg * 48;
            unsigned* dst = &xhl[(reg * 32 + tok) * 49 + dq];
            const float* pv = &v.x;
#pragma unroll
            for (int i = 0; i < 4; i++) {
                unsigned short h = bf16_rne(pv[i]);
                unsigned short lo = bf16_rne(pv[i] - bf16f(h));
                dst[i] = ((unsigned)h << 16) | (unsigned)lo;
            }
        }
    }
    __syncthreads();

    // ---- phase 1a: all waves pull their U-GEMM B-fragments (x cols, region=wv)
    short8 xh0, xl0, xh1, xl1, xh2, xl2;
#pragma unroll
    for (int j = 0; j < 8; j++) {
        int rowb = (wv * 32 + g * 8 + j) * 49;
        unsigned u0 = xhl[rowb + c];
        unsigned u1 = xhl[rowb + 16 + c];
        unsigned u2 = xhl[rowb + 32 + c];
        xh0[j] = (short)(u0 >> 16); xl0[j] = (short)(u0 & 0xffff);
        xh1[j] = (short)(u1 >> 16); xl1[j] = (short)(u1 & 0xffff);
        xh2[j] = (short)(u2 >> 16); xl2[j] = (short)(u2 & 0xffff);
    }

    // ---- phase 1b: waves 0,1 compute w-GEMM (16 tokens each) + exp to LDS
    if (wv < 2) {
        f32x4 accw = {0.f, 0.f, 0.f, 0.f};
#pragma unroll
        for (int kk = 0; kk < 6; kk++) {
            short8 bh = *(const short8*)(php + kk * 512 + l * 8);
            short8 bl = *(const short8*)(plp + kk * 512 + l * 8);
            int dbase = kk * 32 + g * 8;
            int reg = dbase / 48;
            int dq = dbase - reg * 48;
            int rowb = (reg * 32 + wv * 16 + c) * 49 + dq;
            short8 ah, al;
#pragma unroll
            for (int j = 0; j < 8; j++) {
                unsigned u = xhl[rowb + j];
                ah[j] = (short)(u >> 16);
                al[j] = (short)(u & 0xffff);
            }
            accw = __builtin_amdgcn_mfma_f32_16x16x32_bf16(ah, bh, accw, 0, 0, 0);
            accw = __builtin_amdgcn_mfma_f32_16x16x32_bf16(al, bh, accw, 0, 0, 0);
            accw = __builtin_amdgcn_mfma_f32_16x16x32_bf16(ah, bl, accw, 0, 0, 0);
        }
#pragma unroll
        for (int r = 0; r < 4; r++) {
            long row_g = tok0 + wv * 16 + g * 4 + r;   // D: row=(l>>4)*4+r, col=c
            w[row_g * EE + c] = accw[r];
            wexp[(wv * 16 + g * 4 + r) * 17 + c] = __expf(accw[r]);
        }
    }
    __syncthreads();

    // ---- phase 2: A-frag = bf16(exp w), U-MFMA, Z partial
    short8 ad;
    float zl = 0.f;
#pragma unroll
    for (int j = 0; j < 8; j++) {
        float wf = wexp[(g * 8 + j) * 17 + c];
        ad[j] = (short)bf16_rne(wf);
        zl += wf;
    }
    f32x4 acc0 = {0.f, 0.f, 0.f, 0.f};
    f32x4 acc1 = {0.f, 0.f, 0.f, 0.f};
    f32x4 acc2 = {0.f, 0.f, 0.f, 0.f};
    acc0 = __builtin_amdgcn_mfma_f32_16x16x32_bf16(ad, xh0, acc0, 0, 0, 0);
    acc0 = __builtin_amdgcn_mfma_f32_16x16x32_bf16(ad, xl0, acc0, 0, 0, 0);
    acc1 = __builtin_amdgcn_mfma_f32_16x16x32_bf16(ad, xh1, acc1, 0, 0, 0);
    acc1 = __builtin_amdgcn_mfma_f32_16x16x32_bf16(ad, xl1, acc1, 0, 0, 0);
    acc2 = __builtin_amdgcn_mfma_f32_16x16x32_bf16(ad, xh2, acc2, 0, 0, 0);
    acc2 = __builtin_amdgcn_mfma_f32_16x16x32_bf16(ad, xl2, acc2, 0, 0, 0);

    if (wv == 0) {                // Z over the chunk's 32 tokens for e=c
        zl += __shfl_xor(zl, 16);
        zl += __shfl_xor(zl, 32);
        if (l < 16) pZ[((long)ch * BB + b) * EE + c] = zl;
    }

    // D: col = d-in-tile = c, row = e = g*4+r.  pxin[ch][e][b][d]
    float* pb = pxin + (long)ch * (EE * BB * DD) + (long)b * DD;
#pragma unroll
    for (int r = 0; r < 4; r++) {
        int e = g * 4 + r;
        float* pr = pb + (long)e * (BB * DD);
        pr[(wv * 3 + 0) * 16 + c] = acc0[r];
        pr[(wv * 3 + 1) * 16 + c] = acc1[r];
        pr[(wv * 3 + 2) * 16 + c] = acc2[r];
    }
}

// Zg[b][e] = 1 / sum_ch pZ[ch][b][e]
__global__ __launch_bounds__(256)
void k_zred(const float* __restrict__ pZ, float* __restrict__ Zg) {
    int idx = blockIdx.x * 256 + threadIdx.x;
    if (idx >= BB * EE) return;
    float s = 0.f;
#pragma unroll 8
    for (int ch = 0; ch < NCH; ch++)
        s += pZ[(long)ch * (BB * EE) + idx];
    Zg[idx] = 1.f / s;
}

// xin[e][b][d] = (sum_ch pxin) / Z
__global__ __launch_bounds__(256)
void k_xinred(const float* __restrict__ pxin, const float* __restrict__ Zg,
              float* __restrict__ xin) {
    long i = (long)blockIdx.x * 256 + threadIdx.x;   // < EE*BB*DD
    int e = (int)(i / (BB * DD));
    int rem = (int)(i - (long)e * (BB * DD));
    int b = rem / DD;
    float s = 0.f;
#pragma unroll 8
    for (int ch = 0; ch < NCH; ch++)
        s += pxin[(long)ch * (EE * BB * DD) + i];
    xin[i] = s * Zg[b * EE + e];
}

// ================= fallback path (small workspace): old proven kernels =================
__global__ __launch_bounds__(256)
void k_weights(const float* __restrict__ z, const float* __restrict__ a,
               const unsigned short* __restrict__ php,
               const unsigned short* __restrict__ plp,
               float* __restrict__ w) {
    int t = threadIdx.x;
    int wv = t >> 6, l = t & 63;
    long tokbase = ((long)blockIdx.x * 4 + wv) * 16;
    long tokA = tokbase + (l & 15);
    int g = l >> 4;

    short8 bh[6], bl[6], ah[6], al[6];
#pragma unroll
    for (int kk = 0; kk < 6; kk++) {
        bh[kk] = *(const short8*)(php + kk * 512 + l * 8);
        bl[kk] = *(const short8*)(plp + kk * 512 + l * 8);
    }
#pragma unroll
    for (int kk = 0; kk < 6; kk++) {
        int d0 = kk * 32 + g * 8;
        const float* src = (d0 < DZ) ? (z + tokA * DZ + d0)
                                     : (a + tokA * DA + (d0 - DZ));
        float4 v0 = ((const float4*)src)[0];
        float4 v1 = ((const float4*)src)[1];
        float f[8] = {v0.x, v0.y, v0.z, v0.w, v1.x, v1.y, v1.z, v1.w};
#pragma unroll
        for (int j = 0; j < 8; j++) {
            unsigned short h = bf16_rne(f[j]);
            ah[kk][j] = (short)h;
            al[kk][j] = (short)bf16_rne(f[j] - bf16f(h));
        }
    }
    f32x4 acc = {0.f, 0.f, 0.f, 0.f};
#pragma unroll
    for (int kk = 0; kk < 6; kk++)
        acc = __builtin_amdgcn_mfma_f32_16x16x32_bf16(ah[kk], bh[kk], acc, 0, 0, 0);
#pragma unroll
    for (int kk = 0; kk < 6; kk++)
        acc = __builtin_amdgcn_mfma_f32_16x16x32_bf16(al[kk], bh[kk], acc, 0, 0, 0);
#pragma unroll
    for (int kk = 0; kk < 6; kk++)
        acc = __builtin_amdgcn_mfma_f32_16x16x32_bf16(ah[kk], bl[kk], acc, 0, 0, 0);
    int e = l & 15;
#pragma unroll
    for (int r = 0; r < 4; r++) {
        long row = tokbase + g * 4 + r;
        w[row * EE + e] = acc[r];
    }
}

#define RSTR 17
__global__ __launch_bounds__(256)
void k_stats1(const float* __restrict__ w, float* __restrict__ lmax,
              float* __restrict__ lsum) {
    __shared__ float red[256 * RSTR];
    int b = blockIdx.y, c = blockIdx.x, t = threadIdx.x;
    const float* wb = w + ((long)b * NN + c * 512) * EE;
    float m[EE];
#pragma unroll
    for (int e = 0; e < EE; e++) m[e] = -1e30f;
    for (int k = 0; k < 2; k++) {
        const float4* row = (const float4*)(wb + ((long)(k * 256 + t)) * EE);
#pragma unroll
        for (int q = 0; q < 4; q++) {
            float4 v = row[q];
            m[q * 4 + 0] = fmaxf(m[q * 4 + 0], v.x);
            m[q * 4 + 1] = fmaxf(m[q * 4 + 1], v.y);
            m[q * 4 + 2] = fmaxf(m[q * 4 + 2], v.z);
            m[q * 4 + 3] = fmaxf(m[q * 4 + 3], v.w);
        }
    }
#pragma unroll
    for (int e = 0; e < EE; e++) red[t * RSTR + e] = m[e];
    __syncthreads();
    for (int s = 128; s > 0; s >>= 1) {
        if (t < s) {
#pragma unroll
            for (int e = 0; e < EE; e++)
                red[t * RSTR + e] = fmaxf(red[t * RSTR + e], red[(t + s) * RSTR + e]);
        }
        __syncthreads();
    }
    float mg[EE];
#pragma unroll
    for (int e = 0; e < EE; e++) mg[e] = red[e];
    __syncthreads();
    float s_[EE];
#pragma unroll
    for (int e = 0; e < EE; e++) s_[e] = 0.f;
    for (int k = 0; k < 2; k++) {
        const float4* row = (const float4*)(wb + ((long)(k * 256 + t)) * EE);
#pragma unroll
        for (int q = 0; q < 4; q++) {
            float4 v = row[q];
            s_[q * 4 + 0] += __expf(v.x - mg[q * 4 + 0]);
            s_[q * 4 + 1] += __expf(v.y - mg[q * 4 + 1]);
            s_[q * 4 + 2] += __expf(v.z - mg[q * 4 + 2]);
            s_[q * 4 + 3] += __expf(v.w - mg[q * 4 + 3]);
        }
    }
#pragma unroll
    for (int e = 0; e < EE; e++) red[t * RSTR + e] = s_[e];
    __syncthreads();
    for (int s = 128; s > 0; s >>= 1) {
        if (t < s) {
#pragma unroll
            for (int e = 0; e < EE; e++)
                red[t * RSTR + e] += red[(t + s) * RSTR + e];
        }
        __syncthreads();
    }
    if (t < EE) {
        lmax[((long)b * 4 + c) * EE + t] = mg[t];
        lsum[((long)b * 4 + c) * EE + t] = red[t];
    }
}

__global__ __launch_bounds__(256)
void k_stats2(const float* __restrict__ lmax, const float* __restrict__ lsum,
              float* __restrict__ gmax, float* __restrict__ grcp) {
    int idx = blockIdx.x * 256 + threadIdx.x;
    if (idx >= BB * EE) return;
    int b = idx >> 4, e = idx & 15;
    float gm = -1e30f;
#pragma unroll
    for (int c = 0; c < 4; c++)
        gm = fmaxf(gm, lmax[((long)b * 4 + c) * EE + e]);
    float Z = 0.f;
#pragma unroll
    for (int c = 0; c < 4; c++)
        Z += __expf(lmax[((long)b * 4 + c) * EE + e] - gm) * lsum[((long)b * 4 + c) * EE + e];
    gmax[idx] = gm;
    grcp[idx] = 1.f / Z;
}

__global__ __launch_bounds__(192)
void k_xin_scalar(const float* __restrict__ z, const float* __restrict__ a,
                  const float* __restrict__ w, const float* __restrict__ gmax,
                  const float* __restrict__ grcp, float* __restrict__ dst) {
    __shared__ float disp[128 * EE];
    int b = blockIdx.y, chunk = blockIdx.x, t = threadIdx.x;
    const float* wrow = w + ((long)b * NN + (long)chunk * 128) * EE;
    for (int i = t; i < 128 * EE; i += 192) {
        int e = i & 15;
        disp[i] = __expf(wrow[i] - gmax[b * EE + e]) * grcp[b * EE + e];
    }
    __syncthreads();
    const float* xp;
    int stride;
    if (t < DZ) { xp = z + ((long)b * NN + (long)chunk * 128) * DZ + t; stride = DZ; }
    else        { xp = a + ((long)b * NN + (long)chunk * 128) * DA + (t - DZ); stride = DA; }
    float acc[EE];
#pragma unroll
    for (int e = 0; e < EE; e++) acc[e] = 0.f;
    for (int n = 0; n < 128; n++) {
        float xv = xp[(long)n * stride];
        const float4* dp = (const float4*)(disp + n * EE);
#pragma unroll
        for (int q = 0; q < 4; q++) {
            float4 p = dp[q];
            acc[q * 4 + 0] += p.x * xv;
            acc[q * 4 + 1] += p.y * xv;
            acc[q * 4 + 2] += p.z * xv;
            acc[q * 4 + 3] += p.w * xv;
        }
    }
#pragma unroll
    for (int e = 0; e < EE; e++)
        atomicAdd(&dst[((long)e * BB + b) * DD + t], acc[e]);
}

// ---------------- Split-K per-expert GEMM ----------------
template<int K, int OUT, int KSLICE, bool ADD_BIAS>
__global__ __launch_bounds__(256)
void k_gemm(const float* __restrict__ X, const float* __restrict__ W,
            const float* __restrict__ bias, float* __restrict__ Yp) {
    constexpr int SP = KSLICE + 4;
    constexpr int K4 = KSLICE / 4;
    __shared__ float xs[64 * SP];
    int cb = blockIdx.x, ks = blockIdx.y, e = blockIdx.z;
    int t = threadIdx.x;
    int k0 = ks * KSLICE;
    for (int i = t; i < 64 * K4; i += 256) {
        int r = i / K4, k4 = i % K4;
        *(float4*)&xs[r * SP + k4 * 4] =
            *(const float4*)(X + ((long)e * BB + r) * K + k0 + k4 * 4);
    }
    __syncthreads();
    int c = cb * 32 + (t & 7) * 4;
    int r0 = (t >> 3) * 2;
    const float* Wp = W + ((long)e * K + k0) * OUT + c;
    float acc0[4], acc1[4];
#pragma unroll
    for (int j = 0; j < 4; j++) {
        float bv = ADD_BIAS ? bias[(long)e * OUT + c + j] : 0.f;
        acc0[j] = bv;
        acc1[j] = bv;
    }
#pragma unroll 4
    for (int k4 = 0; k4 < K4; k4++) {
        float4 x0 = *(const float4*)&xs[r0 * SP + k4 * 4];
        float4 x1 = *(const float4*)&xs[(r0 + 1) * SP + k4 * 4];
        const float* xp0 = &x0.x;
        const float* xp1 = &x1.x;
#pragma unroll
        for (int j = 0; j < 4; j++) {
            float4 wv = *(const float4*)(Wp + (long)(k4 * 4 + j) * OUT);
            float xa = xp0[j], xb = xp1[j];
            acc0[0] += xa * wv.x; acc0[1] += xa * wv.y;
            acc0[2] += xa * wv.z; acc0[3] += xa * wv.w;
            acc1[0] += xb * wv.x; acc1[1] += xb * wv.y;
            acc1[2] += xb * wv.z; acc1[3] += xb * wv.w;
        }
    }
    float* yp = Yp + ((long)ks * (EE * BB) + (long)e * BB + r0) * OUT + c;
    *(float4*)yp         = make_float4(acc0[0], acc0[1], acc0[2], acc0[3]);
    *(float4*)(yp + OUT) = make_float4(acc1[0], acc1[1], acc1[2], acc1[3]);
}

template<int KS, bool HAS_BIAS>
__global__ __launch_bounds__(256)
void k_lnact(const float* __restrict__ Yp, const float* __restrict__ bias,
             const float* __restrict__ g, const float* __restrict__ be,
             float* __restrict__ Yo) {
    __shared__ float redS[4], redQ[4];
    int row = blockIdx.x, t = threadIdx.x;
    int e = row >> 6;
    float v[2];
#pragma unroll
    for (int j = 0; j < 2; j++) {
        int cj = t + j * 256;
        float s = HAS_BIAS ? bias[(long)e * HH + cj] : 0.f;
#pragma unroll
        for (int ks = 0; ks < KS; ks++)
            s += Yp[((long)ks * (EE * BB) + row) * HH + cj];
        v[j] = s;
    }
    float s = v[0] + v[1];
    float q = v[0] * v[0] + v[1] * v[1];
    for (int off = 32; off > 0; off >>= 1) {
        s += __shfl_xor(s, off);
        q += __shfl_xor(q, off);
    }
    int wave = t >> 6, lane = t & 63;
    if (lane == 0) { redS[wave] = s; redQ[wave] = q; }
    __syncthreads();
    float S = redS[0] + redS[1] + redS[2] + redS[3];
    float Q = redQ[0] + redQ[1] + redQ[2] + redQ[3];
    float mean = S * (1.f / HH);
    float var = Q * (1.f / HH) - mean * mean;
    float rstd = rsqrtf(var + LN_EPS);
#pragma unroll
    for (int j = 0; j < 2; j++) {
        int cj = t + j * 256;
        float gg = g[(long)e * HH + cj], bb = be[(long)e * HH + cj];
        Yo[(long)row * HH + cj] = mishf((v[j] - mean) * rstd * gg + bb);
    }
}

template<int KS>
__global__ __launch_bounds__(256)
void k_fin3(const float* __restrict__ p3, const float* __restrict__ b3,
            float* __restrict__ eout) {
    int t = threadIdx.x;
    int row = blockIdx.x * 2 + (t >> 7);
    int c = t & 127;
    int e = row >> 6, b = row & 63;
    float s = b3[(long)e * DZ + c];
#pragma unroll
    for (int ks = 0; ks < KS; ks++)
        s += p3[((long)ks * (EE * BB) + row) * DZ + c];
    eout[((long)b * EE + e) * DZ + c] = s;
}

// ---------------- K5: combine softmax over E + mix ----------------
__global__ __launch_bounds__(256)
void k_combine(const float* __restrict__ w, const float* __restrict__ eout,
               float* __restrict__ out) {
    __shared__ float comb[64][EE];
    __shared__ float eo[EE * DZ];
    int b = blockIdx.y, n0 = blockIdx.x * 64, t = threadIdx.x;
    for (int i = t; i < EE * DZ; i += 256) eo[i] = eout[(long)b * EE * DZ + i];
    int tok = t >> 2, sub = t & 3;
    const float4 wv = *(const float4*)(w + ((long)b * NN + n0 + tok) * EE + sub * 4);
    float mx = fmaxf(fmaxf(wv.x, wv.y), fmaxf(wv.z, wv.w));
    mx = fmaxf(mx, __shfl_xor(mx, 1, 4));
    mx = fmaxf(mx, __shfl_xor(mx, 2, 4));
    float e0 = __expf(wv.x - mx), e1 = __expf(wv.y - mx);
    float e2 = __expf(wv.z - mx), e3 = __expf(wv.w - mx);
    float s = e0 + e1 + e2 + e3;
    s += __shfl_xor(s, 1, 4);
    s += __shfl_xor(s, 2, 4);
    float rs = 1.f / s;
    comb[tok][sub * 4 + 0] = e0 * rs;
    comb[tok][sub * 4 + 1] = e1 * rs;
    comb[tok][sub * 4 + 2] = e2 * rs;
    comb[tok][sub * 4 + 3] = e3 * rs;
    __syncthreads();
    for (int i = t; i < 64 * DZ; i += 256) {
        int tk = i >> 7, c = i & 127;
        float acc = 0.f;
#pragma unroll
        for (int e = 0; e < EE; e++) acc += comb[tk][e] * eo[e * DZ + c];
        out[((long)b * NN + n0 + tk) * DZ + c] = acc;
    }
}

extern "C" void kernel_launch(void* const* d_in, const int* in_sizes, int n_in,
                              void* d_out, int out_size, void* d_ws, size_t ws_size,
                              hipStream_t stream) {
    const float* z   = (const float*)d_in[0];
    const float* a   = (const float*)d_in[1];
    const float* phi = (const float*)d_in[2];
    const float* W1  = (const float*)d_in[3];
    const float* b1  = (const float*)d_in[4];
    const float* g1  = (const float*)d_in[5];
    const float* be1 = (const float*)d_in[6];
    const float* W2  = (const float*)d_in[7];
    const float* b2  = (const float*)d_in[8];
    const float* g2  = (const float*)d_in[9];
    const float* be2 = (const float*)d_in[10];
    const float* W3  = (const float*)d_in[11];
    const float* b3  = (const float*)d_in[12];
    float* out = (float*)d_out;

    char* p = (char*)d_ws;
    float* w    = (float*)p; p += (size_t)BB * NN * EE * 4;          // 8.39 MB
    float* gmax = (float*)p; p += (size_t)BB * EE * 4;
    float* grcp = (float*)p; p += (size_t)BB * EE * 4;
    float* lmax = (float*)p; p += (size_t)BB * 4 * EE * 4;
    float* lsum = (float*)p; p += (size_t)BB * 4 * EE * 4;
    float* xin  = (float*)p; p += (size_t)BB * EE * DD * 4;          // 786 KB
    unsigned short* php = (unsigned short*)p; p += 6 * 64 * 8 * 2;   // 6 KB
    unsigned short* plp = (unsigned short*)p; p += 6 * 64 * 8 * 2;   // 6 KB
    float* pZ   = (float*)p; p += (size_t)NCH * BB * EE * 4;         // 262 KB
    float* Zg   = (float*)p; p += (size_t)BB * EE * 4;               // 4 KB
    // REGION: time-shared: pxin (NCH*786KB = 50.3 MB, phase A) vs
    // gemm partials + h1 + eout (~11 MB, phase B)
    char* region = p;
    float* pxin = (float*)region;
    float* part = (float*)region;
    float* h1   = (float*)(region + (size_t)4 * EE * BB * HH * 4);
    float* h2   = h1;
    float* eout = (float*)(region + (size_t)4 * EE * BB * HH * 4
                                  + (size_t)EE * BB * HH * 4);
    size_t region_off = (size_t)(region - (char*)d_ws);
    size_t need_full = region_off + (size_t)NCH * EE * BB * DD * 4;
    bool full = ws_size >= need_full;

    k_phipack<<<12, 256, 0, stream>>>(phi, php, plp);

    if (full) {
        k_wxin<<<dim3(NCH, BB), 256, 0, stream>>>(z, a, php, plp, w, pxin, pZ);
        k_zred<<<4, 256, 0, stream>>>(pZ, Zg);
        k_xinred<<<EE * BB * DD / 256, 256, 0, stream>>>(pxin, Zg, xin);
    } else {
        k_weights<<<BB * NN / 64, 256, 0, stream>>>(z, a, php, plp, w);
        k_stats1<<<dim3(4, BB), 256, 0, stream>>>(w, lmax, lsum);
        k_stats2<<<4, 256, 0, stream>>>(lmax, lsum, gmax, grcp);
        hipMemsetAsync(xin, 0, (size_t)BB * EE * DD * 4, stream);
        k_xin_scalar<<<dim3(NN / 128, BB), 192, 0, stream>>>(z, a, w, gmax, grcp, xin);
    }

    // layer 1: 192 -> 512, split-K 2
    k_gemm<DD, HH, 96, false>
        <<<dim3(HH / 32, 2, EE), 256, 0, stream>>>(xin, W1, nullptr, part);
    k_lnact<2, true><<<EE * BB, 256, 0, stream>>>(part, b1, g1, be1, h1);

    // layer 2: 512 -> 512, split-K 4
    k_gemm<HH, HH, 128, false>
        <<<dim3(HH / 32, 4, EE), 256, 0, stream>>>(h1, W2, nullptr, part);
    k_lnact<4, true><<<EE * BB, 256, 0, stream>>>(part, b2, g2, be2, h2);

    // layer 3: 512 -> 128, split-K 8
    k_gemm<HH, DZ, 64, false>
        <<<dim3(DZ / 32, 8, EE), 256, 0, stream>>>(h2, W3, nullptr, part);
    k_fin3<8><<<EE * BB / 2, 256, 0, stream>>>(part, b3, eout);

    k_combine<<<dim3(NN / 64, BB), 256, 0, stream>>>(w, eout, out);
}

// Round 12
// 113.666 us; speedup vs baseline: 1.1918x; 1.1223x over previous
//
#include <hip/hip_runtime.h>
#include <math.h>

#define BB 64
#define NN 2048
#define DZ 128
#define DA 64
#define DD 192
#define EE 16
#define HH 512
#define LN_EPS 1e-5f
#define NCH 32            // 64-token double-chunks per b

typedef __attribute__((ext_vector_type(8))) short short8;
typedef __attribute__((ext_vector_type(4))) float f32x4;

__device__ __forceinline__ float mishf(float x) {
    float sp = (x > 20.f) ? x : log1pf(__expf(x));
    return x * tanhf(sp);
}

__device__ __forceinline__ unsigned short bf16_rne(float f) {
    unsigned u = __float_as_uint(f);
    return (unsigned short)((u + 0x7FFFu + ((u >> 16) & 1u)) >> 16);
}
__device__ __forceinline__ float bf16f(unsigned short h) {
    return __uint_as_float(((unsigned)h) << 16);
}

// ---------------- phi pre-pack: per-lane MFMA B-fragments, bf16 hi/lo ----------------
__global__ __launch_bounds__(256)
void k_phipack(const float* __restrict__ phi, unsigned short* __restrict__ ph,
               unsigned short* __restrict__ pl) {
    int idx = blockIdx.x * 256 + threadIdx.x;
    if (idx >= 6 * 64 * 8) return;
    int j = idx & 7, lane = (idx >> 3) & 63, kk = idx >> 9;
    int e = lane & 15, g = lane >> 4;
    int d = kk * 32 + g * 8 + j;
    float f = phi[d * EE + e];
    unsigned short h = bf16_rne(f);
    ph[idx] = h;
    pl[idx] = bf16_rne(f - bf16f(h));
}

// ---------------- K1 (fused, 2 sub-chunks/block): w = x@phi, U += exp(w)^T @ x ----------
// Block = (64-token double-chunk, b), 4 waves. Sub-chunk s: stage x -> LDS (packed
// hi/lo bf16), w-GEMM (waves 0-1) -> w + wexp[s], then A-frag from wexp, U-MFMA
// accumulating across both sub-chunks; next sub-chunk's stage overlaps U-MFMA.
__global__ __launch_bounds__(256)
void k_wxin(const float* __restrict__ z, const float* __restrict__ a,
            const unsigned short* __restrict__ php,
            const unsigned short* __restrict__ plp,
            float* __restrict__ w, float* __restrict__ pxin,
            float* __restrict__ pZ) {
    __shared__ unsigned int xhl[4 * 32 * 49];   // 25.1 KB (reused per sub-chunk)
    __shared__ float wexp[2][32 * 17];          //  4.4 KB (double-buffered)
    int ch2 = blockIdx.x, b = blockIdx.y;
    int t = threadIdx.x, wv = t >> 6, l = t & 63;
    int g = l >> 4, c = l & 15;

    // stage sub-chunk s: 32 tokens of x -> xhl as packed (hi<<16|lo) bf16
    auto phase0 = [&](int s) {
        long tok0 = (long)b * NN + (long)ch2 * 64 + s * 32;
        const float4* zp = (const float4*)(z + tok0 * DZ);
        const float4* ap = (const float4*)(a + tok0 * DA);
#pragma unroll
        for (int k = 0; k < 6; k++) {
            int f = t + k * 256;                 // < 1536
            int tok = f / 48, q = f - tok * 48;
            float4 v = (q < 32) ? zp[tok * 32 + q] : ap[tok * 16 + (q - 32)];
            int reg = q / 12;
            int dq = q * 4 - reg * 48;
            unsigned* dst = &xhl[(reg * 32 + tok) * 49 + dq];
            const float* pv = &v.x;
#pragma unroll
            for (int i = 0; i < 4; i++) {
                unsigned short h = bf16_rne(pv[i]);
                unsigned short lo = bf16_rne(pv[i] - bf16f(h));
                dst[i] = ((unsigned)h << 16) | (unsigned)lo;
            }
        }
    };

    f32x4 acc0 = {0.f, 0.f, 0.f, 0.f};
    f32x4 acc1 = {0.f, 0.f, 0.f, 0.f};
    f32x4 acc2 = {0.f, 0.f, 0.f, 0.f};
    float zacc = 0.f;

    phase0(0);
    __syncthreads();

#pragma unroll
    for (int s = 0; s < 2; s++) {
        long tok0 = (long)b * NN + (long)ch2 * 64 + s * 32;

        // B-fragments for U-GEMM (x cols, region = wv)
        short8 xh0, xl0, xh1, xl1, xh2, xl2;
#pragma unroll
        for (int j = 0; j < 8; j++) {
            int rowb = (wv * 32 + g * 8 + j) * 49;
            unsigned u0 = xhl[rowb + c];
            unsigned u1 = xhl[rowb + 16 + c];
            unsigned u2 = xhl[rowb + 32 + c];
            xh0[j] = (short)(u0 >> 16); xl0[j] = (short)(u0 & 0xffff);
            xh1[j] = (short)(u1 >> 16); xl1[j] = (short)(u1 & 0xffff);
            xh2[j] = (short)(u2 >> 16); xl2[j] = (short)(u2 & 0xffff);
        }

        // waves 0,1: w-GEMM (16 tokens each) + exp -> wexp[s]
        if (wv < 2) {
            f32x4 accw = {0.f, 0.f, 0.f, 0.f};
#pragma unroll
            for (int kk = 0; kk < 6; kk++) {
                short8 bh = *(const short8*)(php + kk * 512 + l * 8);
                short8 bl = *(const short8*)(plp + kk * 512 + l * 8);
                int dbase = kk * 32 + g * 8;
                int reg = dbase / 48;
                int dq = dbase - reg * 48;
                int rowb = (reg * 32 + wv * 16 + c) * 49 + dq;
                short8 ah, al;
#pragma unroll
                for (int j = 0; j < 8; j++) {
                    unsigned u = xhl[rowb + j];
                    ah[j] = (short)(u >> 16);
                    al[j] = (short)(u & 0xffff);
                }
                accw = __builtin_amdgcn_mfma_f32_16x16x32_bf16(ah, bh, accw, 0, 0, 0);
                accw = __builtin_amdgcn_mfma_f32_16x16x32_bf16(al, bh, accw, 0, 0, 0);
                accw = __builtin_amdgcn_mfma_f32_16x16x32_bf16(ah, bl, accw, 0, 0, 0);
            }
#pragma unroll
            for (int r = 0; r < 4; r++) {
                long row_g = tok0 + wv * 16 + g * 4 + r;
                w[row_g * EE + c] = accw[r];
                wexp[s][(wv * 16 + g * 4 + r) * 17 + c] = __expf(accw[r]);
            }
        }
        __syncthreads();   // wexp[s] visible; ALL xhl reads of sub-chunk s retired

        // A-frag = bf16(exp w); Z partial
        short8 ad;
#pragma unroll
        for (int j = 0; j < 8; j++) {
            float wf = wexp[s][(g * 8 + j) * 17 + c];
            ad[j] = (short)bf16_rne(wf);
            if (wv == 0) zacc += wf;
        }

        // overlap: issue next sub-chunk's stage before the MFMAs
        if (s == 0) phase0(1);

        acc0 = __builtin_amdgcn_mfma_f32_16x16x32_bf16(ad, xh0, acc0, 0, 0, 0);
        acc0 = __builtin_amdgcn_mfma_f32_16x16x32_bf16(ad, xl0, acc0, 0, 0, 0);
        acc1 = __builtin_amdgcn_mfma_f32_16x16x32_bf16(ad, xh1, acc1, 0, 0, 0);
        acc1 = __builtin_amdgcn_mfma_f32_16x16x32_bf16(ad, xl1, acc1, 0, 0, 0);
        acc2 = __builtin_amdgcn_mfma_f32_16x16x32_bf16(ad, xh2, acc2, 0, 0, 0);
        acc2 = __builtin_amdgcn_mfma_f32_16x16x32_bf16(ad, xl2, acc2, 0, 0, 0);

        if (s == 0) __syncthreads();   // next sub-chunk's stage complete
    }

    if (wv == 0) {                // Z over 64 tokens for e=c
        zacc += __shfl_xor(zacc, 16);
        zacc += __shfl_xor(zacc, 32);
        if (l < 16) pZ[((long)ch2 * BB + b) * EE + c] = zacc;
    }

    // D: col = d-in-tile = c, row = e = g*4+r.  pxin[ch2][e][b][d]
    float* pb = pxin + (long)ch2 * (EE * BB * DD) + (long)b * DD;
#pragma unroll
    for (int r = 0; r < 4; r++) {
        int e = g * 4 + r;
        float* pr = pb + (long)e * (BB * DD);
        pr[(wv * 3 + 0) * 16 + c] = acc0[r];
        pr[(wv * 3 + 1) * 16 + c] = acc1[r];
        pr[(wv * 3 + 2) * 16 + c] = acc2[r];
    }
}

// Zg[b][e] = 1 / sum_ch pZ[ch][b][e]
__global__ __launch_bounds__(256)
void k_zred(const float* __restrict__ pZ, float* __restrict__ Zg) {
    int idx = blockIdx.x * 256 + threadIdx.x;
    if (idx >= BB * EE) return;
    float s = 0.f;
#pragma unroll 8
    for (int ch = 0; ch < NCH; ch++)
        s += pZ[(long)ch * (BB * EE) + idx];
    Zg[idx] = 1.f / s;
}

// xin[e][b][d] = (sum_ch pxin) / Z
__global__ __launch_bounds__(256)
void k_xinred(const float* __restrict__ pxin, const float* __restrict__ Zg,
              float* __restrict__ xin) {
    long i = (long)blockIdx.x * 256 + threadIdx.x;
    int e = (int)(i / (BB * DD));
    int rem = (int)(i - (long)e * (BB * DD));
    int b = rem / DD;
    float s = 0.f;
#pragma unroll 8
    for (int ch = 0; ch < NCH; ch++)
        s += pxin[(long)ch * (EE * BB * DD) + i];
    xin[i] = s * Zg[b * EE + e];
}

// ================= fallback path (small workspace): old proven kernels =================
__global__ __launch_bounds__(256)
void k_weights(const float* __restrict__ z, const float* __restrict__ a,
               const unsigned short* __restrict__ php,
               const unsigned short* __restrict__ plp,
               float* __restrict__ w) {
    int t = threadIdx.x;
    int wv = t >> 6, l = t & 63;
    long tokbase = ((long)blockIdx.x * 4 + wv) * 16;
    long tokA = tokbase + (l & 15);
    int g = l >> 4;

    short8 bh[6], bl[6], ah[6], al[6];
#pragma unroll
    for (int kk = 0; kk < 6; kk++) {
        bh[kk] = *(const short8*)(php + kk * 512 + l * 8);
        bl[kk] = *(const short8*)(plp + kk * 512 + l * 8);
    }
#pragma unroll
    for (int kk = 0; kk < 6; kk++) {
        int d0 = kk * 32 + g * 8;
        const float* src = (d0 < DZ) ? (z + tokA * DZ + d0)
                                     : (a + tokA * DA + (d0 - DZ));
        float4 v0 = ((const float4*)src)[0];
        float4 v1 = ((const float4*)src)[1];
        float f[8] = {v0.x, v0.y, v0.z, v0.w, v1.x, v1.y, v1.z, v1.w};
#pragma unroll
        for (int j = 0; j < 8; j++) {
            unsigned short h = bf16_rne(f[j]);
            ah[kk][j] = (short)h;
            al[kk][j] = (short)bf16_rne(f[j] - bf16f(h));
        }
    }
    f32x4 acc = {0.f, 0.f, 0.f, 0.f};
#pragma unroll
    for (int kk = 0; kk < 6; kk++)
        acc = __builtin_amdgcn_mfma_f32_16x16x32_bf16(ah[kk], bh[kk], acc, 0, 0, 0);
#pragma unroll
    for (int kk = 0; kk < 6; kk++)
        acc = __builtin_amdgcn_mfma_f32_16x16x32_bf16(al[kk], bh[kk], acc, 0, 0, 0);
#pragma unroll
    for (int kk = 0; kk < 6; kk++)
        acc = __builtin_amdgcn_mfma_f32_16x16x32_bf16(ah[kk], bl[kk], acc, 0, 0, 0);
    int e = l & 15;
#pragma unroll
    for (int r = 0; r < 4; r++) {
        long row = tokbase + g * 4 + r;
        w[row * EE + e] = acc[r];
    }
}

#define RSTR 17
__global__ __launch_bounds__(256)
void k_stats1(const float* __restrict__ w, float* __restrict__ lmax,
              float* __restrict__ lsum) {
    __shared__ float red[256 * RSTR];
    int b = blockIdx.y, c = blockIdx.x, t = threadIdx.x;
    const float* wb = w + ((long)b * NN + c * 512) * EE;
    float m[EE];
#pragma unroll
    for (int e = 0; e < EE; e++) m[e] = -1e30f;
    for (int k = 0; k < 2; k++) {
        const float4* row = (const float4*)(wb + ((long)(k * 256 + t)) * EE);
#pragma unroll
        for (int q = 0; q < 4; q++) {
            float4 v = row[q];
            m[q * 4 + 0] = fmaxf(m[q * 4 + 0], v.x);
            m[q * 4 + 1] = fmaxf(m[q * 4 + 1], v.y);
            m[q * 4 + 2] = fmaxf(m[q * 4 + 2], v.z);
            m[q * 4 + 3] = fmaxf(m[q * 4 + 3], v.w);
        }
    }
#pragma unroll
    for (int e = 0; e < EE; e++) red[t * RSTR + e] = m[e];
    __syncthreads();
    for (int s = 128; s > 0; s >>= 1) {
        if (t < s) {
#pragma unroll
            for (int e = 0; e < EE; e++)
                red[t * RSTR + e] = fmaxf(red[t * RSTR + e], red[(t + s) * RSTR + e]);
        }
        __syncthreads();
    }
    float mg[EE];
#pragma unroll
    for (int e = 0; e < EE; e++) mg[e] = red[e];
    __syncthreads();
    float s_[EE];
#pragma unroll
    for (int e = 0; e < EE; e++) s_[e] = 0.f;
    for (int k = 0; k < 2; k++) {
        const float4* row = (const float4*)(wb + ((long)(k * 256 + t)) * EE);
#pragma unroll
        for (int q = 0; q < 4; q++) {
            float4 v = row[q];
            s_[q * 4 + 0] += __expf(v.x - mg[q * 4 + 0]);
            s_[q * 4 + 1] += __expf(v.y - mg[q * 4 + 1]);
            s_[q * 4 + 2] += __expf(v.z - mg[q * 4 + 2]);
            s_[q * 4 + 3] += __expf(v.w - mg[q * 4 + 3]);
        }
    }
#pragma unroll
    for (int e = 0; e < EE; e++) red[t * RSTR + e] = s_[e];
    __syncthreads();
    for (int s = 128; s > 0; s >>= 1) {
        if (t < s) {
#pragma unroll
            for (int e = 0; e < EE; e++)
                red[t * RSTR + e] += red[(t + s) * RSTR + e];
        }
        __syncthreads();
    }
    if (t < EE) {
        lmax[((long)b * 4 + c) * EE + t] = mg[t];
        lsum[((long)b * 4 + c) * EE + t] = red[t];
    }
}

__global__ __launch_bounds__(256)
void k_stats2(const float* __restrict__ lmax, const float* __restrict__ lsum,
              float* __restrict__ gmax, float* __restrict__ grcp) {
    int idx = blockIdx.x * 256 + threadIdx.x;
    if (idx >= BB * EE) return;
    int b = idx >> 4, e = idx & 15;
    float gm = -1e30f;
#pragma unroll
    for (int c = 0; c < 4; c++)
        gm = fmaxf(gm, lmax[((long)b * 4 + c) * EE + e]);
    float Z = 0.f;
#pragma unroll
    for (int c = 0; c < 4; c++)
        Z += __expf(lmax[((long)b * 4 + c) * EE + e] - gm) * lsum[((long)b * 4 + c) * EE + e];
    gmax[idx] = gm;
    grcp[idx] = 1.f / Z;
}

__global__ __launch_bounds__(192)
void k_xin_scalar(const float* __restrict__ z, const float* __restrict__ a,
                  const float* __restrict__ w, const float* __restrict__ gmax,
                  const float* __restrict__ grcp, float* __restrict__ dst) {
    __shared__ float disp[128 * EE];
    int b = blockIdx.y, chunk = blockIdx.x, t = threadIdx.x;
    const float* wrow = w + ((long)b * NN + (long)chunk * 128) * EE;
    for (int i = t; i < 128 * EE; i += 192) {
        int e = i & 15;
        disp[i] = __expf(wrow[i] - gmax[b * EE + e]) * grcp[b * EE + e];
    }
    __syncthreads();
    const float* xp;
    int stride;
    if (t < DZ) { xp = z + ((long)b * NN + (long)chunk * 128) * DZ + t; stride = DZ; }
    else        { xp = a + ((long)b * NN + (long)chunk * 128) * DA + (t - DZ); stride = DA; }
    float acc[EE];
#pragma unroll
    for (int e = 0; e < EE; e++) acc[e] = 0.f;
    for (int n = 0; n < 128; n++) {
        float xv = xp[(long)n * stride];
        const float4* dp = (const float4*)(disp + n * EE);
#pragma unroll
        for (int q = 0; q < 4; q++) {
            float4 p = dp[q];
            acc[q * 4 + 0] += p.x * xv;
            acc[q * 4 + 1] += p.y * xv;
            acc[q * 4 + 2] += p.z * xv;
            acc[q * 4 + 3] += p.w * xv;
        }
    }
#pragma unroll
    for (int e = 0; e < EE; e++)
        atomicAdd(&dst[((long)e * BB + b) * DD + t], acc[e]);
}

// ---------------- Split-K per-expert GEMM ----------------
template<int K, int OUT, int KSLICE, bool ADD_BIAS>
__global__ __launch_bounds__(256)
void k_gemm(const float* __restrict__ X, const float* __restrict__ W,
            const float* __restrict__ bias, float* __restrict__ Yp) {
    constexpr int SP = KSLICE + 4;
    constexpr int K4 = KSLICE / 4;
    __shared__ float xs[64 * SP];
    int cb = blockIdx.x, ks = blockIdx.y, e = blockIdx.z;
    int t = threadIdx.x;
    int k0 = ks * KSLICE;
    for (int i = t; i < 64 * K4; i += 256) {
        int r = i / K4, k4 = i % K4;
        *(float4*)&xs[r * SP + k4 * 4] =
            *(const float4*)(X + ((long)e * BB + r) * K + k0 + k4 * 4);
    }
    __syncthreads();
    int c = cb * 32 + (t & 7) * 4;
    int r0 = (t >> 3) * 2;
    const float* Wp = W + ((long)e * K + k0) * OUT + c;
    float acc0[4], acc1[4];
#pragma unroll
    for (int j = 0; j < 4; j++) {
        float bv = ADD_BIAS ? bias[(long)e * OUT + c + j] : 0.f;
        acc0[j] = bv;
        acc1[j] = bv;
    }
#pragma unroll 4
    for (int k4 = 0; k4 < K4; k4++) {
        float4 x0 = *(const float4*)&xs[r0 * SP + k4 * 4];
        float4 x1 = *(const float4*)&xs[(r0 + 1) * SP + k4 * 4];
        const float* xp0 = &x0.x;
        const float* xp1 = &x1.x;
#pragma unroll
        for (int j = 0; j < 4; j++) {
            float4 wv = *(const float4*)(Wp + (long)(k4 * 4 + j) * OUT);
            float xa = xp0[j], xb = xp1[j];
            acc0[0] += xa * wv.x; acc0[1] += xa * wv.y;
            acc0[2] += xa * wv.z; acc0[3] += xa * wv.w;
            acc1[0] += xb * wv.x; acc1[1] += xb * wv.y;
            acc1[2] += xb * wv.z; acc1[3] += xb * wv.w;
        }
    }
    float* yp = Yp + ((long)ks * (EE * BB) + (long)e * BB + r0) * OUT + c;
    *(float4*)yp         = make_float4(acc0[0], acc0[1], acc0[2], acc0[3]);
    *(float4*)(yp + OUT) = make_float4(acc1[0], acc1[1], acc1[2], acc1[3]);
}

template<int KS, bool HAS_BIAS>
__global__ __launch_bounds__(256)
void k_lnact(const float* __restrict__ Yp, const float* __restrict__ bias,
             const float* __restrict__ g, const float* __restrict__ be,
             float* __restrict__ Yo) {
    __shared__ float redS[4], redQ[4];
    int row = blockIdx.x, t = threadIdx.x;
    int e = row >> 6;
    float v[2];
#pragma unroll
    for (int j = 0; j < 2; j++) {
        int cj = t + j * 256;
        float s = HAS_BIAS ? bias[(long)e * HH + cj] : 0.f;
#pragma unroll
        for (int ks = 0; ks < KS; ks++)
            s += Yp[((long)ks * (EE * BB) + row) * HH + cj];
        v[j] = s;
    }
    float s = v[0] + v[1];
    float q = v[0] * v[0] + v[1] * v[1];
    for (int off = 32; off > 0; off >>= 1) {
        s += __shfl_xor(s, off);
        q += __shfl_xor(q, off);
    }
    int wave = t >> 6, lane = t & 63;
    if (lane == 0) { redS[wave] = s; redQ[wave] = q; }
    __syncthreads();
    float S = redS[0] + redS[1] + redS[2] + redS[3];
    float Q = redQ[0] + redQ[1] + redQ[2] + redQ[3];
    float mean = S * (1.f / HH);
    float var = Q * (1.f / HH) - mean * mean;
    float rstd = rsqrtf(var + LN_EPS);
#pragma unroll
    for (int j = 0; j < 2; j++) {
        int cj = t + j * 256;
        float gg = g[(long)e * HH + cj], bb = be[(long)e * HH + cj];
        Yo[(long)row * HH + cj] = mishf((v[j] - mean) * rstd * gg + bb);
    }
}

template<int KS>
__global__ __launch_bounds__(256)
void k_fin3(const float* __restrict__ p3, const float* __restrict__ b3,
            float* __restrict__ eout) {
    int t = threadIdx.x;
    int row = blockIdx.x * 2 + (t >> 7);
    int c = t & 127;
    int e = row >> 6, b = row & 63;
    float s = b3[(long)e * DZ + c];
#pragma unroll
    for (int ks = 0; ks < KS; ks++)
        s += p3[((long)ks * (EE * BB) + row) * DZ + c];
    eout[((long)b * EE + e) * DZ + c] = s;
}

// ---------------- K5: combine softmax over E + mix ----------------
__global__ __launch_bounds__(256)
void k_combine(const float* __restrict__ w, const float* __restrict__ eout,
               float* __restrict__ out) {
    __shared__ float comb[64][EE];
    __shared__ float eo[EE * DZ];
    int b = blockIdx.y, n0 = blockIdx.x * 64, t = threadIdx.x;
    for (int i = t; i < EE * DZ; i += 256) eo[i] = eout[(long)b * EE * DZ + i];
    int tok = t >> 2, sub = t & 3;
    const float4 wv = *(const float4*)(w + ((long)b * NN + n0 + tok) * EE + sub * 4);
    float mx = fmaxf(fmaxf(wv.x, wv.y), fmaxf(wv.z, wv.w));
    mx = fmaxf(mx, __shfl_xor(mx, 1, 4));
    mx = fmaxf(mx, __shfl_xor(mx, 2, 4));
    float e0 = __expf(wv.x - mx), e1 = __expf(wv.y - mx);
    float e2 = __expf(wv.z - mx), e3 = __expf(wv.w - mx);
    float s = e0 + e1 + e2 + e3;
    s += __shfl_xor(s, 1, 4);
    s += __shfl_xor(s, 2, 4);
    float rs = 1.f / s;
    comb[tok][sub * 4 + 0] = e0 * rs;
    comb[tok][sub * 4 + 1] = e1 * rs;
    comb[tok][sub * 4 + 2] = e2 * rs;
    comb[tok][sub * 4 + 3] = e3 * rs;
    __syncthreads();
    for (int i = t; i < 64 * DZ; i += 256) {
        int tk = i >> 7, c = i & 127;
        float acc = 0.f;
#pragma unroll
        for (int e = 0; e < EE; e++) acc += comb[tk][e] * eo[e * DZ + c];
        out[((long)b * NN + n0 + tk) * DZ + c] = acc;
    }
}

extern "C" void kernel_launch(void* const* d_in, const int* in_sizes, int n_in,
                              void* d_out, int out_size, void* d_ws, size_t ws_size,
                              hipStream_t stream) {
    const float* z   = (const float*)d_in[0];
    const float* a   = (const float*)d_in[1];
    const float* phi = (const float*)d_in[2];
    const float* W1  = (const float*)d_in[3];
    const float* b1  = (const float*)d_in[4];
    const float* g1  = (const float*)d_in[5];
    const float* be1 = (const float*)d_in[6];
    const float* W2  = (const float*)d_in[7];
    const float* b2  = (const float*)d_in[8];
    const float* g2  = (const float*)d_in[9];
    const float* be2 = (const float*)d_in[10];
    const float* W3  = (const float*)d_in[11];
    const float* b3  = (const float*)d_in[12];
    float* out = (float*)d_out;

    char* p = (char*)d_ws;
    float* w    = (float*)p; p += (size_t)BB * NN * EE * 4;          // 8.39 MB
    float* gmax = (float*)p; p += (size_t)BB * EE * 4;
    float* grcp = (float*)p; p += (size_t)BB * EE * 4;
    float* lmax = (float*)p; p += (size_t)BB * 4 * EE * 4;
    float* lsum = (float*)p; p += (size_t)BB * 4 * EE * 4;
    float* xin  = (float*)p; p += (size_t)BB * EE * DD * 4;          // 786 KB
    unsigned short* php = (unsigned short*)p; p += 6 * 64 * 8 * 2;   // 6 KB
    unsigned short* plp = (unsigned short*)p; p += 6 * 64 * 8 * 2;   // 6 KB
    float* pZ   = (float*)p; p += (size_t)NCH * BB * EE * 4;         // 131 KB
    float* Zg   = (float*)p; p += (size_t)BB * EE * 4;               // 4 KB
    // REGION: time-shared: pxin (NCH*786KB = 25.2 MB, phase A) vs
    // gemm partials + h1 + eout (~11 MB, phase B)
    char* region = p;
    float* pxin = (float*)region;
    float* part = (float*)region;
    float* h1   = (float*)(region + (size_t)4 * EE * BB * HH * 4);
    float* h2   = h1;
    float* eout = (float*)(region + (size_t)4 * EE * BB * HH * 4
                                  + (size_t)EE * BB * HH * 4);
    size_t region_off = (size_t)(region - (char*)d_ws);
    size_t need_full = region_off + (size_t)NCH * EE * BB * DD * 4;
    bool full = ws_size >= need_full;

    k_phipack<<<12, 256, 0, stream>>>(phi, php, plp);

    if (full) {
        k_wxin<<<dim3(NCH, BB), 256, 0, stream>>>(z, a, php, plp, w, pxin, pZ);
        k_zred<<<4, 256, 0, stream>>>(pZ, Zg);
        k_xinred<<<EE * BB * DD / 256, 256, 0, stream>>>(pxin, Zg, xin);
    } else {
        k_weights<<<BB * NN / 64, 256, 0, stream>>>(z, a, php, plp, w);
        k_stats1<<<dim3(4, BB), 256, 0, stream>>>(w, lmax, lsum);
        k_stats2<<<4, 256, 0, stream>>>(lmax, lsum, gmax, grcp);
        hipMemsetAsync(xin, 0, (size_t)BB * EE * DD * 4, stream);
        k_xin_scalar<<<dim3(NN / 128, BB), 192, 0, stream>>>(z, a, w, gmax, grcp, xin);
    }

    // layer 1: 192 -> 512, split-K 2
    k_gemm<DD, HH, 96, false>
        <<<dim3(HH / 32, 2, EE), 256, 0, stream>>>(xin, W1, nullptr, part);
    k_lnact<2, true><<<EE * BB, 256, 0, stream>>>(part, b1, g1, be1, h1);

    // layer 2: 512 -> 512, split-K 4
    k_gemm<HH, HH, 128, false>
        <<<dim3(HH / 32, 4, EE), 256, 0, stream>>>(h1, W2, nullptr, part);
    k_lnact<4, true><<<EE * BB, 256, 0, stream>>>(part, b2, g2, be2, h2);

    // layer 3: 512 -> 128, split-K 8
    k_gemm<HH, DZ, 64, false>
        <<<dim3(DZ / 32, 8, EE), 256, 0, stream>>>(h2, W3, nullptr, part);
    k_fin3<8><<<EE * BB / 2, 256, 0, stream>>>(part, b3, eout);

    k_combine<<<dim3(NN / 64, BB), 256, 0, stream>>>(w, eout, out);
}

// Round 13
// 109.691 us; speedup vs baseline: 1.2350x; 1.0362x over previous
//
#include <hip/hip_runtime.h>
#include <math.h>

#define BB 64
#define NN 2048
#define DZ 128
#define DA 64
#define DD 192
#define EE 16
#define HH 512
#define LN_EPS 1e-5f
#define NCH 32            // 64-token blocks per b

typedef __attribute__((ext_vector_type(8))) short short8;
typedef __attribute__((ext_vector_type(4))) float f32x4;

__device__ __forceinline__ float mishf(float x) {
    float sp = (x > 20.f) ? x : log1pf(__expf(x));
    return x * tanhf(sp);
}

__device__ __forceinline__ unsigned short bf16_rne(float f) {
    unsigned u = __float_as_uint(f);
    return (unsigned short)((u + 0x7FFFu + ((u >> 16) & 1u)) >> 16);
}
__device__ __forceinline__ float bf16f(unsigned short h) {
    return __uint_as_float(((unsigned)h) << 16);
}

// ---------------- phi pre-pack: per-lane MFMA B-fragments, bf16 hi/lo ----------------
__global__ __launch_bounds__(256)
void k_phipack(const float* __restrict__ phi, unsigned short* __restrict__ ph,
               unsigned short* __restrict__ pl) {
    int idx = blockIdx.x * 256 + threadIdx.x;
    if (idx >= 6 * 64 * 8) return;
    int j = idx & 7, lane = (idx >> 3) & 63, kk = idx >> 9;
    int e = lane & 15, g = lane >> 4;
    int d = kk * 32 + g * 8 + j;
    float f = phi[d * EE + e];
    unsigned short h = bf16_rne(f);
    ph[idx] = h;
    pl[idx] = bf16_rne(f - bf16f(h));
}

// ---------------- K1 v4: per-wave register-streaming w-GEMM + one-barrier U-GEMM ------
// Block = 64 tokens (4 waves x 16-token tiles), b. Phase A: each wave loads its tile
// from global (float4, r6 k_weights pattern), 3-term split w-GEMM, writes w + exp(w),
// and deposits x-hi into LDS xp[tokpair][196] u32 (pair-interleaved, via shfl_xor(1),
// b128 writes at bank floor). ONE barrier. Phase B: U-GEMM, hi-only x, conflict-free
// u32 B-frag reads. pxin/pZ partials as before.
__global__ __launch_bounds__(256)
void k_wxin(const float* __restrict__ z, const float* __restrict__ a,
            const unsigned short* __restrict__ php,
            const unsigned short* __restrict__ plp,
            float* __restrict__ w, float* __restrict__ pxin,
            float* __restrict__ pZ) {
    __shared__ unsigned int xp[32 * 196];   // 24.5 KB: [tp][d], u32 = hi(tok 2tp)|hi(2tp+1)<<16
    __shared__ float wexp[64 * 17];         //  4.35 KB
    int ch2 = blockIdx.x, b = blockIdx.y;
    int t = threadIdx.x, wv = t >> 6, l = t & 63;
    int g = l >> 4, c = l & 15;
    long tokA = (long)b * NN + (long)ch2 * 64 + wv * 16 + c;

    // ---- phase A ----
    f32x4 accw = {0.f, 0.f, 0.f, 0.f};
#pragma unroll
    for (int kk = 0; kk < 6; kk++) {
        int d0 = kk * 32 + g * 8;                 // 8-elem chunk never straddles z/a
        const float* src = (d0 < DZ) ? (z + tokA * DZ + d0)
                                     : (a + tokA * DA + (d0 - DZ));
        float4 v0 = ((const float4*)src)[0];
        float4 v1 = ((const float4*)src)[1];
        float f[8] = {v0.x, v0.y, v0.z, v0.w, v1.x, v1.y, v1.z, v1.w};
        short8 ah, al;
#pragma unroll
        for (int j = 0; j < 8; j++) {
            unsigned short h = bf16_rne(f[j]);
            ah[j] = (short)h;
            al[j] = (short)bf16_rne(f[j] - bf16f(h));
        }
        short8 bh = *(const short8*)(php + kk * 512 + l * 8);
        short8 bl = *(const short8*)(plp + kk * 512 + l * 8);
        accw = __builtin_amdgcn_mfma_f32_16x16x32_bf16(ah, bh, accw, 0, 0, 0);
        accw = __builtin_amdgcn_mfma_f32_16x16x32_bf16(al, bh, accw, 0, 0, 0);
        accw = __builtin_amdgcn_mfma_f32_16x16x32_bf16(ah, bl, accw, 0, 0, 0);

        // pair-pack hi with neighbor token (lane c^1) and write 16B to xp
        unsigned au[4], bu[4];
#pragma unroll
        for (int i = 0; i < 4; i++)
            au[i] = ((unsigned)(unsigned short)ah[2 * i]) |
                    (((unsigned)(unsigned short)ah[2 * i + 1]) << 16);
#pragma unroll
        for (int i = 0; i < 4; i++) bu[i] = (unsigned)__shfl_xor((int)au[i], 1);
        unsigned o0, o1, o2, o3;
        if ((c & 1) == 0) {                       // write words d0+0..3
            o0 = (au[0] & 0xffffu) | (bu[0] << 16);
            o1 = (au[0] >> 16) | (bu[0] & 0xffff0000u);
            o2 = (au[1] & 0xffffu) | (bu[1] << 16);
            o3 = (au[1] >> 16) | (bu[1] & 0xffff0000u);
        } else {                                  // write words d0+4..7
            o0 = (bu[2] & 0xffffu) | (au[2] << 16);
            o1 = (bu[2] >> 16) | (au[2] & 0xffff0000u);
            o2 = (bu[3] & 0xffffu) | (au[3] << 16);
            o3 = (bu[3] >> 16) | (au[3] & 0xffff0000u);
        }
        int tp = wv * 8 + (c >> 1);
        uint4* dst = (uint4*)&xp[tp * 196 + d0 + (c & 1) * 4];
        uint4 ov; ov.x = o0; ov.y = o1; ov.z = o2; ov.w = o3;
        *dst = ov;
    }
#pragma unroll
    for (int r = 0; r < 4; r++) {
        long row = (long)b * NN + (long)ch2 * 64 + wv * 16 + g * 4 + r;
        w[row * EE + c] = accw[r];
        wexp[(wv * 16 + g * 4 + r) * 17 + c] = __expf(accw[r]);
    }
    __syncthreads();

    // ---- phase B: U-GEMM (hi-only), 2 k-steps of 32 tokens ----
    f32x4 acc0 = {0.f, 0.f, 0.f, 0.f};
    f32x4 acc1 = {0.f, 0.f, 0.f, 0.f};
    f32x4 acc2 = {0.f, 0.f, 0.f, 0.f};
    float zacc = 0.f;
#pragma unroll
    for (int ks = 0; ks < 2; ks++) {
        short8 ad;
#pragma unroll
        for (int j = 0; j < 8; j++) {
            float wf = wexp[(ks * 32 + g * 8 + j) * 17 + c];
            ad[j] = (short)bf16_rne(wf);
            zacc += wf;
        }
#pragma unroll
        for (int dt = 0; dt < 3; dt++) {
            int d = wv * 48 + dt * 16 + c;
            int tpb = (ks * 16 + g * 4) * 196 + d;
            unsigned u0 = xp[tpb];
            unsigned u1 = xp[tpb + 196];
            unsigned u2 = xp[tpb + 392];
            unsigned u3 = xp[tpb + 588];
            short8 xb;
            xb[0] = (short)(u0 & 0xffffu); xb[1] = (short)(u0 >> 16);
            xb[2] = (short)(u1 & 0xffffu); xb[3] = (short)(u1 >> 16);
            xb[4] = (short)(u2 & 0xffffu); xb[5] = (short)(u2 >> 16);
            xb[6] = (short)(u3 & 0xffffu); xb[7] = (short)(u3 >> 16);
            if (dt == 0)
                acc0 = __builtin_amdgcn_mfma_f32_16x16x32_bf16(ad, xb, acc0, 0, 0, 0);
            else if (dt == 1)
                acc1 = __builtin_amdgcn_mfma_f32_16x16x32_bf16(ad, xb, acc1, 0, 0, 0);
            else
                acc2 = __builtin_amdgcn_mfma_f32_16x16x32_bf16(ad, xb, acc2, 0, 0, 0);
        }
    }

    zacc += __shfl_xor(zacc, 16);
    zacc += __shfl_xor(zacc, 32);
    if (wv == 0 && l < 16)
        pZ[((long)ch2 * BB + b) * EE + c] = zacc;

    float* pb = pxin + (long)ch2 * (EE * BB * DD) + (long)b * DD;
#pragma unroll
    for (int r = 0; r < 4; r++) {
        int e = g * 4 + r;
        float* pr = pb + (long)e * (BB * DD);
        pr[wv * 48 + c]      = acc0[r];
        pr[wv * 48 + 16 + c] = acc1[r];
        pr[wv * 48 + 32 + c] = acc2[r];
    }
}

// Zg[b][e] = 1 / sum_ch pZ[ch][b][e]
__global__ __launch_bounds__(256)
void k_zred(const float* __restrict__ pZ, float* __restrict__ Zg) {
    int idx = blockIdx.x * 256 + threadIdx.x;
    if (idx >= BB * EE) return;
    float s = 0.f;
#pragma unroll 8
    for (int ch = 0; ch < NCH; ch++)
        s += pZ[(long)ch * (BB * EE) + idx];
    Zg[idx] = 1.f / s;
}

// xin[e][b][d] = (sum_ch pxin) / Z
__global__ __launch_bounds__(256)
void k_xinred(const float* __restrict__ pxin, const float* __restrict__ Zg,
              float* __restrict__ xin) {
    long i = (long)blockIdx.x * 256 + threadIdx.x;
    int e = (int)(i / (BB * DD));
    int rem = (int)(i - (long)e * (BB * DD));
    int b = rem / DD;
    float s = 0.f;
#pragma unroll 8
    for (int ch = 0; ch < NCH; ch++)
        s += pxin[(long)ch * (EE * BB * DD) + i];
    xin[i] = s * Zg[b * EE + e];
}

// ================= fallback path (small workspace): old proven kernels =================
__global__ __launch_bounds__(256)
void k_weights(const float* __restrict__ z, const float* __restrict__ a,
               const unsigned short* __restrict__ php,
               const unsigned short* __restrict__ plp,
               float* __restrict__ w) {
    int t = threadIdx.x;
    int wv = t >> 6, l = t & 63;
    long tokbase = ((long)blockIdx.x * 4 + wv) * 16;
    long tokA = tokbase + (l & 15);
    int g = l >> 4;

    short8 bh[6], bl[6], ah[6], al[6];
#pragma unroll
    for (int kk = 0; kk < 6; kk++) {
        bh[kk] = *(const short8*)(php + kk * 512 + l * 8);
        bl[kk] = *(const short8*)(plp + kk * 512 + l * 8);
    }
#pragma unroll
    for (int kk = 0; kk < 6; kk++) {
        int d0 = kk * 32 + g * 8;
        const float* src = (d0 < DZ) ? (z + tokA * DZ + d0)
                                     : (a + tokA * DA + (d0 - DZ));
        float4 v0 = ((const float4*)src)[0];
        float4 v1 = ((const float4*)src)[1];
        float f[8] = {v0.x, v0.y, v0.z, v0.w, v1.x, v1.y, v1.z, v1.w};
#pragma unroll
        for (int j = 0; j < 8; j++) {
            unsigned short h = bf16_rne(f[j]);
            ah[kk][j] = (short)h;
            al[kk][j] = (short)bf16_rne(f[j] - bf16f(h));
        }
    }
    f32x4 acc = {0.f, 0.f, 0.f, 0.f};
#pragma unroll
    for (int kk = 0; kk < 6; kk++)
        acc = __builtin_amdgcn_mfma_f32_16x16x32_bf16(ah[kk], bh[kk], acc, 0, 0, 0);
#pragma unroll
    for (int kk = 0; kk < 6; kk++)
        acc = __builtin_amdgcn_mfma_f32_16x16x32_bf16(al[kk], bh[kk], acc, 0, 0, 0);
#pragma unroll
    for (int kk = 0; kk < 6; kk++)
        acc = __builtin_amdgcn_mfma_f32_16x16x32_bf16(ah[kk], bl[kk], acc, 0, 0, 0);
    int e = l & 15;
#pragma unroll
    for (int r = 0; r < 4; r++) {
        long row = tokbase + g * 4 + r;
        w[row * EE + e] = acc[r];
    }
}

#define RSTR 17
__global__ __launch_bounds__(256)
void k_stats1(const float* __restrict__ w, float* __restrict__ lmax,
              float* __restrict__ lsum) {
    __shared__ float red[256 * RSTR];
    int b = blockIdx.y, c = blockIdx.x, t = threadIdx.x;
    const float* wb = w + ((long)b * NN + c * 512) * EE;
    float m[EE];
#pragma unroll
    for (int e = 0; e < EE; e++) m[e] = -1e30f;
    for (int k = 0; k < 2; k++) {
        const float4* row = (const float4*)(wb + ((long)(k * 256 + t)) * EE);
#pragma unroll
        for (int q = 0; q < 4; q++) {
            float4 v = row[q];
            m[q * 4 + 0] = fmaxf(m[q * 4 + 0], v.x);
            m[q * 4 + 1] = fmaxf(m[q * 4 + 1], v.y);
            m[q * 4 + 2] = fmaxf(m[q * 4 + 2], v.z);
            m[q * 4 + 3] = fmaxf(m[q * 4 + 3], v.w);
        }
    }
#pragma unroll
    for (int e = 0; e < EE; e++) red[t * RSTR + e] = m[e];
    __syncthreads();
    for (int s = 128; s > 0; s >>= 1) {
        if (t < s) {
#pragma unroll
            for (int e = 0; e < EE; e++)
                red[t * RSTR + e] = fmaxf(red[t * RSTR + e], red[(t + s) * RSTR + e]);
        }
        __syncthreads();
    }
    float mg[EE];
#pragma unroll
    for (int e = 0; e < EE; e++) mg[e] = red[e];
    __syncthreads();
    float s_[EE];
#pragma unroll
    for (int e = 0; e < EE; e++) s_[e] = 0.f;
    for (int k = 0; k < 2; k++) {
        const float4* row = (const float4*)(wb + ((long)(k * 256 + t)) * EE);
#pragma unroll
        for (int q = 0; q < 4; q++) {
            float4 v = row[q];
            s_[q * 4 + 0] += __expf(v.x - mg[q * 4 + 0]);
            s_[q * 4 + 1] += __expf(v.y - mg[q * 4 + 1]);
            s_[q * 4 + 2] += __expf(v.z - mg[q * 4 + 2]);
            s_[q * 4 + 3] += __expf(v.w - mg[q * 4 + 3]);
        }
    }
#pragma unroll
    for (int e = 0; e < EE; e++) red[t * RSTR + e] = s_[e];
    __syncthreads();
    for (int s = 128; s > 0; s >>= 1) {
        if (t < s) {
#pragma unroll
            for (int e = 0; e < EE; e++)
                red[t * RSTR + e] += red[(t + s) * RSTR + e];
        }
        __syncthreads();
    }
    if (t < EE) {
        lmax[((long)b * 4 + c) * EE + t] = mg[t];
        lsum[((long)b * 4 + c) * EE + t] = red[t];
    }
}

__global__ __launch_bounds__(256)
void k_stats2(const float* __restrict__ lmax, const float* __restrict__ lsum,
              float* __restrict__ gmax, float* __restrict__ grcp) {
    int idx = blockIdx.x * 256 + threadIdx.x;
    if (idx >= BB * EE) return;
    int b = idx >> 4, e = idx & 15;
    float gm = -1e30f;
#pragma unroll
    for (int c = 0; c < 4; c++)
        gm = fmaxf(gm, lmax[((long)b * 4 + c) * EE + e]);
    float Z = 0.f;
#pragma unroll
    for (int c = 0; c < 4; c++)
        Z += __expf(lmax[((long)b * 4 + c) * EE + e] - gm) * lsum[((long)b * 4 + c) * EE + e];
    gmax[idx] = gm;
    grcp[idx] = 1.f / Z;
}

__global__ __launch_bounds__(192)
void k_xin_scalar(const float* __restrict__ z, const float* __restrict__ a,
                  const float* __restrict__ w, const float* __restrict__ gmax,
                  const float* __restrict__ grcp, float* __restrict__ dst) {
    __shared__ float disp[128 * EE];
    int b = blockIdx.y, chunk = blockIdx.x, t = threadIdx.x;
    const float* wrow = w + ((long)b * NN + (long)chunk * 128) * EE;
    for (int i = t; i < 128 * EE; i += 192) {
        int e = i & 15;
        disp[i] = __expf(wrow[i] - gmax[b * EE + e]) * grcp[b * EE + e];
    }
    __syncthreads();
    const float* xp_;
    int stride;
    if (t < DZ) { xp_ = z + ((long)b * NN + (long)chunk * 128) * DZ + t; stride = DZ; }
    else        { xp_ = a + ((long)b * NN + (long)chunk * 128) * DA + (t - DZ); stride = DA; }
    float acc[EE];
#pragma unroll
    for (int e = 0; e < EE; e++) acc[e] = 0.f;
    for (int n = 0; n < 128; n++) {
        float xv = xp_[(long)n * stride];
        const float4* dp = (const float4*)(disp + n * EE);
#pragma unroll
        for (int q = 0; q < 4; q++) {
            float4 p = dp[q];
            acc[q * 4 + 0] += p.x * xv;
            acc[q * 4 + 1] += p.y * xv;
            acc[q * 4 + 2] += p.z * xv;
            acc[q * 4 + 3] += p.w * xv;
        }
    }
#pragma unroll
    for (int e = 0; e < EE; e++)
        atomicAdd(&dst[((long)e * BB + b) * DD + t], acc[e]);
}

// ---------------- Split-K per-expert GEMM ----------------
template<int K, int OUT, int KSLICE, bool ADD_BIAS>
__global__ __launch_bounds__(256)
void k_gemm(const float* __restrict__ X, const float* __restrict__ W,
            const float* __restrict__ bias, float* __restrict__ Yp) {
    constexpr int SP = KSLICE + 4;
    constexpr int K4 = KSLICE / 4;
    __shared__ float xs[64 * SP];
    int cb = blockIdx.x, ks = blockIdx.y, e = blockIdx.z;
    int t = threadIdx.x;
    int k0 = ks * KSLICE;
    for (int i = t; i < 64 * K4; i += 256) {
        int r = i / K4, k4 = i % K4;
        *(float4*)&xs[r * SP + k4 * 4] =
            *(const float4*)(X + ((long)e * BB + r) * K + k0 + k4 * 4);
    }
    __syncthreads();
    int c = cb * 32 + (t & 7) * 4;
    int r0 = (t >> 3) * 2;
    const float* Wp = W + ((long)e * K + k0) * OUT + c;
    float acc0[4], acc1[4];
#pragma unroll
    for (int j = 0; j < 4; j++) {
        float bv = ADD_BIAS ? bias[(long)e * OUT + c + j] : 0.f;
        acc0[j] = bv;
        acc1[j] = bv;
    }
#pragma unroll 4
    for (int k4 = 0; k4 < K4; k4++) {
        float4 x0 = *(const float4*)&xs[r0 * SP + k4 * 4];
        float4 x1 = *(const float4*)&xs[(r0 + 1) * SP + k4 * 4];
        const float* xp0 = &x0.x;
        const float* xp1 = &x1.x;
#pragma unroll
        for (int j = 0; j < 4; j++) {
            float4 wv = *(const float4*)(Wp + (long)(k4 * 4 + j) * OUT);
            float xa = xp0[j], xb = xp1[j];
            acc0[0] += xa * wv.x; acc0[1] += xa * wv.y;
            acc0[2] += xa * wv.z; acc0[3] += xa * wv.w;
            acc1[0] += xb * wv.x; acc1[1] += xb * wv.y;
            acc1[2] += xb * wv.z; acc1[3] += xb * wv.w;
        }
    }
    float* yp = Yp + ((long)ks * (EE * BB) + (long)e * BB + r0) * OUT + c;
    *(float4*)yp         = make_float4(acc0[0], acc0[1], acc0[2], acc0[3]);
    *(float4*)(yp + OUT) = make_float4(acc1[0], acc1[1], acc1[2], acc1[3]);
}

template<int KS, bool HAS_BIAS>
__global__ __launch_bounds__(256)
void k_lnact(const float* __restrict__ Yp, const float* __restrict__ bias,
             const float* __restrict__ g, const float* __restrict__ be,
             float* __restrict__ Yo) {
    __shared__ float redS[4], redQ[4];
    int row = blockIdx.x, t = threadIdx.x;
    int e = row >> 6;
    float v[2];
#pragma unroll
    for (int j = 0; j < 2; j++) {
        int cj = t + j * 256;
        float s = HAS_BIAS ? bias[(long)e * HH + cj] : 0.f;
#pragma unroll
        for (int ks = 0; ks < KS; ks++)
            s += Yp[((long)ks * (EE * BB) + row) * HH + cj];
        v[j] = s;
    }
    float s = v[0] + v[1];
    float q = v[0] * v[0] + v[1] * v[1];
    for (int off = 32; off > 0; off >>= 1) {
        s += __shfl_xor(s, off);
        q += __shfl_xor(q, off);
    }
    int wave = t >> 6, lane = t & 63;
    if (lane == 0) { redS[wave] = s; redQ[wave] = q; }
    __syncthreads();
    float S = redS[0] + redS[1] + redS[2] + redS[3];
    float Q = redQ[0] + redQ[1] + redQ[2] + redQ[3];
    float mean = S * (1.f / HH);
    float var = Q * (1.f / HH) - mean * mean;
    float rstd = rsqrtf(var + LN_EPS);
#pragma unroll
    for (int j = 0; j < 2; j++) {
        int cj = t + j * 256;
        float gg = g[(long)e * HH + cj], bb = be[(long)e * HH + cj];
        Yo[(long)row * HH + cj] = mishf((v[j] - mean) * rstd * gg + bb);
    }
}

template<int KS>
__global__ __launch_bounds__(256)
void k_fin3(const float* __restrict__ p3, const float* __restrict__ b3,
            float* __restrict__ eout) {
    int t = threadIdx.x;
    int row = blockIdx.x * 2 + (t >> 7);
    int c = t & 127;
    int e = row >> 6, b = row & 63;
    float s = b3[(long)e * DZ + c];
#pragma unroll
    for (int ks = 0; ks < KS; ks++)
        s += p3[((long)ks * (EE * BB) + row) * DZ + c];
    eout[((long)b * EE + e) * DZ + c] = s;
}

// ---------------- K5: combine softmax over E + mix (vectorized stores) ----------------
__global__ __launch_bounds__(256)
void k_combine(const float* __restrict__ w, const float* __restrict__ eout,
               float* __restrict__ out) {
    __shared__ float comb[64][EE];
    __shared__ float eo[EE * DZ];
    int b = blockIdx.y, n0 = blockIdx.x * 64, t = threadIdx.x;
    for (int i = t; i < EE * DZ / 4; i += 256)
        ((float4*)eo)[i] = ((const float4*)(eout + (long)b * EE * DZ))[i];
    int tok = t >> 2, sub = t & 3;
    const float4 wv = *(const float4*)(w + ((long)b * NN + n0 + tok) * EE + sub * 4);
    float mx = fmaxf(fmaxf(wv.x, wv.y), fmaxf(wv.z, wv.w));
    mx = fmaxf(mx, __shfl_xor(mx, 1, 4));
    mx = fmaxf(mx, __shfl_xor(mx, 2, 4));
    float e0 = __expf(wv.x - mx), e1 = __expf(wv.y - mx);
    float e2 = __expf(wv.z - mx), e3 = __expf(wv.w - mx);
    float s = e0 + e1 + e2 + e3;
    s += __shfl_xor(s, 1, 4);
    s += __shfl_xor(s, 2, 4);
    float rs = 1.f / s;
    comb[tok][sub * 4 + 0] = e0 * rs;
    comb[tok][sub * 4 + 1] = e1 * rs;
    comb[tok][sub * 4 + 2] = e2 * rs;
    comb[tok][sub * 4 + 3] = e3 * rs;
    __syncthreads();

    for (int i = t; i < 64 * (DZ / 4); i += 256) {
        int tk = i >> 5, c4 = (i & 31) * 4;
        float ax = 0.f, ay = 0.f, az = 0.f, aw = 0.f;
#pragma unroll
        for (int e = 0; e < EE; e++) {
            float cw = comb[tk][e];
            float4 ev = *(const float4*)&eo[e * DZ + c4];
            ax += cw * ev.x; ay += cw * ev.y;
            az += cw * ev.z; aw += cw * ev.w;
        }
        *(float4*)&out[((long)b * NN + n0 + tk) * DZ + c4] = make_float4(ax, ay, az, aw);
    }
}

extern "C" void kernel_launch(void* const* d_in, const int* in_sizes, int n_in,
                              void* d_out, int out_size, void* d_ws, size_t ws_size,
                              hipStream_t stream) {
    const float* z   = (const float*)d_in[0];
    const float* a   = (const float*)d_in[1];
    const float* phi = (const float*)d_in[2];
    const float* W1  = (const float*)d_in[3];
    const float* b1  = (const float*)d_in[4];
    const float* g1  = (const float*)d_in[5];
    const float* be1 = (const float*)d_in[6];
    const float* W2  = (const float*)d_in[7];
    const float* b2  = (const float*)d_in[8];
    const float* g2  = (const float*)d_in[9];
    const float* be2 = (const float*)d_in[10];
    const float* W3  = (const float*)d_in[11];
    const float* b3  = (const float*)d_in[12];
    float* out = (float*)d_out;

    char* p = (char*)d_ws;
    float* w    = (float*)p; p += (size_t)BB * NN * EE * 4;          // 8.39 MB
    float* gmax = (float*)p; p += (size_t)BB * EE * 4;
    float* grcp = (float*)p; p += (size_t)BB * EE * 4;
    float* lmax = (float*)p; p += (size_t)BB * 4 * EE * 4;
    float* lsum = (float*)p; p += (size_t)BB * 4 * EE * 4;
    float* xin  = (float*)p; p += (size_t)BB * EE * DD * 4;          // 786 KB
    unsigned short* php = (unsigned short*)p; p += 6 * 64 * 8 * 2;   // 6 KB
    unsigned short* plp = (unsigned short*)p; p += 6 * 64 * 8 * 2;   // 6 KB
    float* pZ   = (float*)p; p += (size_t)NCH * BB * EE * 4;         // 131 KB
    float* Zg   = (float*)p; p += (size_t)BB * EE * 4;               // 4 KB
    // REGION: time-shared: pxin (NCH*786KB = 25.2 MB, phase A) vs
    // gemm partials + h1 + eout (~11 MB, phase B)
    char* region = p;
    float* pxin = (float*)region;
    float* part = (float*)region;
    float* h1   = (float*)(region + (size_t)4 * EE * BB * HH * 4);
    float* h2   = h1;
    float* eout = (float*)(region + (size_t)4 * EE * BB * HH * 4
                                  + (size_t)EE * BB * HH * 4);
    size_t region_off = (size_t)(region - (char*)d_ws);
    size_t need_full = region_off + (size_t)NCH * EE * BB * DD * 4;
    bool full = ws_size >= need_full;

    k_phipack<<<12, 256, 0, stream>>>(phi, php, plp);

    if (full) {
        k_wxin<<<dim3(NCH, BB), 256, 0, stream>>>(z, a, php, plp, w, pxin, pZ);
        k_zred<<<4, 256, 0, stream>>>(pZ, Zg);
        k_xinred<<<EE * BB * DD / 256, 256, 0, stream>>>(pxin, Zg, xin);
    } else {
        k_weights<<<BB * NN / 64, 256, 0, stream>>>(z, a, php, plp, w);
        k_stats1<<<dim3(4, BB), 256, 0, stream>>>(w, lmax, lsum);
        k_stats2<<<4, 256, 0, stream>>>(lmax, lsum, gmax, grcp);
        hipMemsetAsync(xin, 0, (size_t)BB * EE * DD * 4, stream);
        k_xin_scalar<<<dim3(NN / 128, BB), 192, 0, stream>>>(z, a, w, gmax, grcp, xin);
    }

    // layer 1: 192 -> 512, split-K 2
    k_gemm<DD, HH, 96, false>
        <<<dim3(HH / 32, 2, EE), 256, 0, stream>>>(xin, W1, nullptr, part);
    k_lnact<2, true><<<EE * BB, 256, 0, stream>>>(part, b1, g1, be1, h1);

    // layer 2: 512 -> 512, split-K 4
    k_gemm<HH, HH, 128, false>
        <<<dim3(HH / 32, 4, EE), 256, 0, stream>>>(h1, W2, nullptr, part);
    k_lnact<4, true><<<EE * BB, 256, 0, stream>>>(part, b2, g2, be2, h2);

    // layer 3: 512 -> 128, split-K 8
    k_gemm<HH, DZ, 64, false>
        <<<dim3(DZ / 32, 8, EE), 256, 0, stream>>>(h2, W3, nullptr, part);
    k_fin3<8><<<EE * BB / 2, 256, 0, stream>>>(part, b3, eout);

    k_combine<<<dim3(NN / 64, BB), 256, 0, stream>>>(w, eout, out);
}

// Round 14
// 108.097 us; speedup vs baseline: 1.2533x; 1.0147x over previous
//
#include <hip/hip_runtime.h>
#include <math.h>

#define BB 64
#define NN 2048
#define DZ 128
#define DA 64
#define DD 192
#define EE 16
#define HH 512
#define LN_EPS 1e-5f
#define NCH 32            // 64-token blocks per b

typedef __attribute__((ext_vector_type(8))) short short8;
typedef __attribute__((ext_vector_type(4))) float f32x4;

__device__ __forceinline__ float mishf(float x) {
    float sp = (x > 20.f) ? x : log1pf(__expf(x));
    return x * tanhf(sp);
}

__device__ __forceinline__ unsigned short bf16_rne(float f) {
    unsigned u = __float_as_uint(f);
    return (unsigned short)((u + 0x7FFFu + ((u >> 16) & 1u)) >> 16);
}
__device__ __forceinline__ float bf16f(unsigned short h) {
    return __uint_as_float(((unsigned)h) << 16);
}

// ---------------- phi pre-pack: per-lane MFMA B-fragments, bf16 hi/lo ----------------
__global__ __launch_bounds__(256)
void k_phipack(const float* __restrict__ phi, unsigned short* __restrict__ ph,
               unsigned short* __restrict__ pl) {
    int idx = blockIdx.x * 256 + threadIdx.x;
    if (idx >= 6 * 64 * 8) return;
    int j = idx & 7, lane = (idx >> 3) & 63, kk = idx >> 9;
    int e = lane & 15, g = lane >> 4;
    int d = kk * 32 + g * 8 + j;
    float f = phi[d * EE + e];
    unsigned short h = bf16_rne(f);
    ph[idx] = h;
    pl[idx] = bf16_rne(f - bf16f(h));
}

// ---------------- K1 v5: loads-first streaming w-GEMM + one-barrier U-GEMM ------------
// Block = 64 tokens (4 waves x 16-token tiles), b. Phase A: ALL 12 x float4 loads
// issued first into vx[12] (r6 k_weights pattern -> load-issue parallelism), phi into
// bh/bl[6]; then convert/MFMA/pack loop (LDS xp writes, pair-interleaved). One barrier.
// Phase B: U-GEMM, hi-only x, conflict-free u32 B-frag reads. pxin/pZ partials.
__global__ __launch_bounds__(256)
void k_wxin(const float* __restrict__ z, const float* __restrict__ a,
            const unsigned short* __restrict__ php,
            const unsigned short* __restrict__ plp,
            float* __restrict__ w, float* __restrict__ pxin,
            float* __restrict__ pZ) {
    __shared__ unsigned int xp[32 * 196];   // 24.5 KB: [tp][d], u32 = hi(tok 2tp)|hi(2tp+1)<<16
    __shared__ float wexp[64 * 17];         //  4.35 KB
    int ch2 = blockIdx.x, b = blockIdx.y;
    int t = threadIdx.x, wv = t >> 6, l = t & 63;
    int g = l >> 4, c = l & 15;
    long tokA = (long)b * NN + (long)ch2 * 64 + wv * 16 + c;

    // ---- phase A0: issue ALL independent loads first (keeps them in flight together)
    float4 vx[12];
#pragma unroll
    for (int kk = 0; kk < 6; kk++) {
        int d0 = kk * 32 + g * 8;                 // 8-elem chunk never straddles z/a
        const float* src = (d0 < DZ) ? (z + tokA * DZ + d0)
                                     : (a + tokA * DA + (d0 - DZ));
        vx[2 * kk]     = ((const float4*)src)[0];
        vx[2 * kk + 1] = ((const float4*)src)[1];
    }
    short8 bh[6], bl[6];
#pragma unroll
    for (int kk = 0; kk < 6; kk++) {
        bh[kk] = *(const short8*)(php + kk * 512 + l * 8);
        bl[kk] = *(const short8*)(plp + kk * 512 + l * 8);
    }

    // ---- phase A1: convert + w-GEMM + pack x-hi to LDS
    f32x4 accw = {0.f, 0.f, 0.f, 0.f};
#pragma unroll
    for (int kk = 0; kk < 6; kk++) {
        int d0 = kk * 32 + g * 8;
        float f[8] = {vx[2 * kk].x,     vx[2 * kk].y,     vx[2 * kk].z,     vx[2 * kk].w,
                      vx[2 * kk + 1].x, vx[2 * kk + 1].y, vx[2 * kk + 1].z, vx[2 * kk + 1].w};
        short8 ah, al;
#pragma unroll
        for (int j = 0; j < 8; j++) {
            unsigned short h = bf16_rne(f[j]);
            ah[j] = (short)h;
            al[j] = (short)bf16_rne(f[j] - bf16f(h));
        }
        accw = __builtin_amdgcn_mfma_f32_16x16x32_bf16(ah, bh[kk], accw, 0, 0, 0);
        accw = __builtin_amdgcn_mfma_f32_16x16x32_bf16(al, bh[kk], accw, 0, 0, 0);
        accw = __builtin_amdgcn_mfma_f32_16x16x32_bf16(ah, bl[kk], accw, 0, 0, 0);

        // pair-pack hi with neighbor token (lane c^1) and write 16B to xp
        unsigned au[4], bu[4];
#pragma unroll
        for (int i = 0; i < 4; i++)
            au[i] = ((unsigned)(unsigned short)ah[2 * i]) |
                    (((unsigned)(unsigned short)ah[2 * i + 1]) << 16);
#pragma unroll
        for (int i = 0; i < 4; i++) bu[i] = (unsigned)__shfl_xor((int)au[i], 1);
        unsigned o0, o1, o2, o3;
        if ((c & 1) == 0) {                       // write words d0+0..3
            o0 = (au[0] & 0xffffu) | (bu[0] << 16);
            o1 = (au[0] >> 16) | (bu[0] & 0xffff0000u);
            o2 = (au[1] & 0xffffu) | (bu[1] << 16);
            o3 = (au[1] >> 16) | (bu[1] & 0xffff0000u);
        } else {                                  // write words d0+4..7
            o0 = (bu[2] & 0xffffu) | (au[2] << 16);
            o1 = (bu[2] >> 16) | (au[2] & 0xffff0000u);
            o2 = (bu[3] & 0xffffu) | (au[3] << 16);
            o3 = (bu[3] >> 16) | (au[3] & 0xffff0000u);
        }
        int tp = wv * 8 + (c >> 1);
        uint4* dst = (uint4*)&xp[tp * 196 + d0 + (c & 1) * 4];
        uint4 ov; ov.x = o0; ov.y = o1; ov.z = o2; ov.w = o3;
        *dst = ov;
    }
#pragma unroll
    for (int r = 0; r < 4; r++) {
        long row = (long)b * NN + (long)ch2 * 64 + wv * 16 + g * 4 + r;
        w[row * EE + c] = accw[r];
        wexp[(wv * 16 + g * 4 + r) * 17 + c] = __expf(accw[r]);
    }
    __syncthreads();

    // ---- phase B: U-GEMM (hi-only), 2 k-steps of 32 tokens ----
    f32x4 acc0 = {0.f, 0.f, 0.f, 0.f};
    f32x4 acc1 = {0.f, 0.f, 0.f, 0.f};
    f32x4 acc2 = {0.f, 0.f, 0.f, 0.f};
    float zacc = 0.f;
#pragma unroll
    for (int ks = 0; ks < 2; ks++) {
        short8 ad;
#pragma unroll
        for (int j = 0; j < 8; j++) {
            float wf = wexp[(ks * 32 + g * 8 + j) * 17 + c];
            ad[j] = (short)bf16_rne(wf);
            zacc += wf;
        }
#pragma unroll
        for (int dt = 0; dt < 3; dt++) {
            int d = wv * 48 + dt * 16 + c;
            int tpb = (ks * 16 + g * 4) * 196 + d;
            unsigned u0 = xp[tpb];
            unsigned u1 = xp[tpb + 196];
            unsigned u2 = xp[tpb + 392];
            unsigned u3 = xp[tpb + 588];
            short8 xb;
            xb[0] = (short)(u0 & 0xffffu); xb[1] = (short)(u0 >> 16);
            xb[2] = (short)(u1 & 0xffffu); xb[3] = (short)(u1 >> 16);
            xb[4] = (short)(u2 & 0xffffu); xb[5] = (short)(u2 >> 16);
            xb[6] = (short)(u3 & 0xffffu); xb[7] = (short)(u3 >> 16);
            if (dt == 0)
                acc0 = __builtin_amdgcn_mfma_f32_16x16x32_bf16(ad, xb, acc0, 0, 0, 0);
            else if (dt == 1)
                acc1 = __builtin_amdgcn_mfma_f32_16x16x32_bf16(ad, xb, acc1, 0, 0, 0);
            else
                acc2 = __builtin_amdgcn_mfma_f32_16x16x32_bf16(ad, xb, acc2, 0, 0, 0);
        }
    }

    zacc += __shfl_xor(zacc, 16);
    zacc += __shfl_xor(zacc, 32);
    if (wv == 0 && l < 16)
        pZ[((long)ch2 * BB + b) * EE + c] = zacc;

    float* pb = pxin + (long)ch2 * (EE * BB * DD) + (long)b * DD;
#pragma unroll
    for (int r = 0; r < 4; r++) {
        int e = g * 4 + r;
        float* pr = pb + (long)e * (BB * DD);
        pr[wv * 48 + c]      = acc0[r];
        pr[wv * 48 + 16 + c] = acc1[r];
        pr[wv * 48 + 32 + c] = acc2[r];
    }
}

// Zg[b][e] = 1 / sum_ch pZ[ch][b][e]
__global__ __launch_bounds__(256)
void k_zred(const float* __restrict__ pZ, float* __restrict__ Zg) {
    int idx = blockIdx.x * 256 + threadIdx.x;
    if (idx >= BB * EE) return;
    float s = 0.f;
#pragma unroll 8
    for (int ch = 0; ch < NCH; ch++)
        s += pZ[(long)ch * (BB * EE) + idx];
    Zg[idx] = 1.f / s;
}

// xin[e][b][d] = (sum_ch pxin) / Z
__global__ __launch_bounds__(256)
void k_xinred(const float* __restrict__ pxin, const float* __restrict__ Zg,
              float* __restrict__ xin) {
    long i = (long)blockIdx.x * 256 + threadIdx.x;
    int e = (int)(i / (BB * DD));
    int rem = (int)(i - (long)e * (BB * DD));
    int b = rem / DD;
    float s = 0.f;
#pragma unroll 8
    for (int ch = 0; ch < NCH; ch++)
        s += pxin[(long)ch * (EE * BB * DD) + i];
    xin[i] = s * Zg[b * EE + e];
}

// ================= fallback path (small workspace): old proven kernels =================
__global__ __launch_bounds__(256)
void k_weights(const float* __restrict__ z, const float* __restrict__ a,
               const unsigned short* __restrict__ php,
               const unsigned short* __restrict__ plp,
               float* __restrict__ w) {
    int t = threadIdx.x;
    int wv = t >> 6, l = t & 63;
    long tokbase = ((long)blockIdx.x * 4 + wv) * 16;
    long tokA = tokbase + (l & 15);
    int g = l >> 4;

    short8 bh[6], bl[6], ah[6], al[6];
#pragma unroll
    for (int kk = 0; kk < 6; kk++) {
        bh[kk] = *(const short8*)(php + kk * 512 + l * 8);
        bl[kk] = *(const short8*)(plp + kk * 512 + l * 8);
    }
#pragma unroll
    for (int kk = 0; kk < 6; kk++) {
        int d0 = kk * 32 + g * 8;
        const float* src = (d0 < DZ) ? (z + tokA * DZ + d0)
                                     : (a + tokA * DA + (d0 - DZ));
        float4 v0 = ((const float4*)src)[0];
        float4 v1 = ((const float4*)src)[1];
        float f[8] = {v0.x, v0.y, v0.z, v0.w, v1.x, v1.y, v1.z, v1.w};
#pragma unroll
        for (int j = 0; j < 8; j++) {
            unsigned short h = bf16_rne(f[j]);
            ah[kk][j] = (short)h;
            al[kk][j] = (short)bf16_rne(f[j] - bf16f(h));
        }
    }
    f32x4 acc = {0.f, 0.f, 0.f, 0.f};
#pragma unroll
    for (int kk = 0; kk < 6; kk++)
        acc = __builtin_amdgcn_mfma_f32_16x16x32_bf16(ah[kk], bh[kk], acc, 0, 0, 0);
#pragma unroll
    for (int kk = 0; kk < 6; kk++)
        acc = __builtin_amdgcn_mfma_f32_16x16x32_bf16(al[kk], bh[kk], acc, 0, 0, 0);
#pragma unroll
    for (int kk = 0; kk < 6; kk++)
        acc = __builtin_amdgcn_mfma_f32_16x16x32_bf16(ah[kk], bl[kk], acc, 0, 0, 0);
    int e = l & 15;
#pragma unroll
    for (int r = 0; r < 4; r++) {
        long row = tokbase + g * 4 + r;
        w[row * EE + e] = acc[r];
    }
}

#define RSTR 17
__global__ __launch_bounds__(256)
void k_stats1(const float* __restrict__ w, float* __restrict__ lmax,
              float* __restrict__ lsum) {
    __shared__ float red[256 * RSTR];
    int b = blockIdx.y, c = blockIdx.x, t = threadIdx.x;
    const float* wb = w + ((long)b * NN + c * 512) * EE;
    float m[EE];
#pragma unroll
    for (int e = 0; e < EE; e++) m[e] = -1e30f;
    for (int k = 0; k < 2; k++) {
        const float4* row = (const float4*)(wb + ((long)(k * 256 + t)) * EE);
#pragma unroll
        for (int q = 0; q < 4; q++) {
            float4 v = row[q];
            m[q * 4 + 0] = fmaxf(m[q * 4 + 0], v.x);
            m[q * 4 + 1] = fmaxf(m[q * 4 + 1], v.y);
            m[q * 4 + 2] = fmaxf(m[q * 4 + 2], v.z);
            m[q * 4 + 3] = fmaxf(m[q * 4 + 3], v.w);
        }
    }
#pragma unroll
    for (int e = 0; e < EE; e++) red[t * RSTR + e] = m[e];
    __syncthreads();
    for (int s = 128; s > 0; s >>= 1) {
        if (t < s) {
#pragma unroll
            for (int e = 0; e < EE; e++)
                red[t * RSTR + e] = fmaxf(red[t * RSTR + e], red[(t + s) * RSTR + e]);
        }
        __syncthreads();
    }
    float mg[EE];
#pragma unroll
    for (int e = 0; e < EE; e++) mg[e] = red[e];
    __syncthreads();
    float s_[EE];
#pragma unroll
    for (int e = 0; e < EE; e++) s_[e] = 0.f;
    for (int k = 0; k < 2; k++) {
        const float4* row = (const float4*)(wb + ((long)(k * 256 + t)) * EE);
#pragma unroll
        for (int q = 0; q < 4; q++) {
            float4 v = row[q];
            s_[q * 4 + 0] += __expf(v.x - mg[q * 4 + 0]);
            s_[q * 4 + 1] += __expf(v.y - mg[q * 4 + 1]);
            s_[q * 4 + 2] += __expf(v.z - mg[q * 4 + 2]);
            s_[q * 4 + 3] += __expf(v.w - mg[q * 4 + 3]);
        }
    }
#pragma unroll
    for (int e = 0; e < EE; e++) red[t * RSTR + e] = s_[e];
    __syncthreads();
    for (int s = 128; s > 0; s >>= 1) {
        if (t < s) {
#pragma unroll
            for (int e = 0; e < EE; e++)
                red[t * RSTR + e] += red[(t + s) * RSTR + e];
        }
        __syncthreads();
    }
    if (t < EE) {
        lmax[((long)b * 4 + c) * EE + t] = mg[t];
        lsum[((long)b * 4 + c) * EE + t] = red[t];
    }
}

__global__ __launch_bounds__(256)
void k_stats2(const float* __restrict__ lmax, const float* __restrict__ lsum,
              float* __restrict__ gmax, float* __restrict__ grcp) {
    int idx = blockIdx.x * 256 + threadIdx.x;
    if (idx >= BB * EE) return;
    int b = idx >> 4, e = idx & 15;
    float gm = -1e30f;
#pragma unroll
    for (int c = 0; c < 4; c++)
        gm = fmaxf(gm, lmax[((long)b * 4 + c) * EE + e]);
    float Z = 0.f;
#pragma unroll
    for (int c = 0; c < 4; c++)
        Z += __expf(lmax[((long)b * 4 + c) * EE + e] - gm) * lsum[((long)b * 4 + c) * EE + e];
    gmax[idx] = gm;
    grcp[idx] = 1.f / Z;
}

__global__ __launch_bounds__(192)
void k_xin_scalar(const float* __restrict__ z, const float* __restrict__ a,
                  const float* __restrict__ w, const float* __restrict__ gmax,
                  const float* __restrict__ grcp, float* __restrict__ dst) {
    __shared__ float disp[128 * EE];
    int b = blockIdx.y, chunk = blockIdx.x, t = threadIdx.x;
    const float* wrow = w + ((long)b * NN + (long)chunk * 128) * EE;
    for (int i = t; i < 128 * EE; i += 192) {
        int e = i & 15;
        disp[i] = __expf(wrow[i] - gmax[b * EE + e]) * grcp[b * EE + e];
    }
    __syncthreads();
    const float* xp_;
    int stride;
    if (t < DZ) { xp_ = z + ((long)b * NN + (long)chunk * 128) * DZ + t; stride = DZ; }
    else        { xp_ = a + ((long)b * NN + (long)chunk * 128) * DA + (t - DZ); stride = DA; }
    float acc[EE];
#pragma unroll
    for (int e = 0; e < EE; e++) acc[e] = 0.f;
    for (int n = 0; n < 128; n++) {
        float xv = xp_[(long)n * stride];
        const float4* dp = (const float4*)(disp + n * EE);
#pragma unroll
        for (int q = 0; q < 4; q++) {
            float4 p = dp[q];
            acc[q * 4 + 0] += p.x * xv;
            acc[q * 4 + 1] += p.y * xv;
            acc[q * 4 + 2] += p.z * xv;
            acc[q * 4 + 3] += p.w * xv;
        }
    }
#pragma unroll
    for (int e = 0; e < EE; e++)
        atomicAdd(&dst[((long)e * BB + b) * DD + t], acc[e]);
}

// ---------------- Split-K per-expert GEMM ----------------
template<int K, int OUT, int KSLICE, bool ADD_BIAS>
__global__ __launch_bounds__(256)
void k_gemm(const float* __restrict__ X, const float* __restrict__ W,
            const float* __restrict__ bias, float* __restrict__ Yp) {
    constexpr int SP = KSLICE + 4;
    constexpr int K4 = KSLICE / 4;
    __shared__ float xs[64 * SP];
    int cb = blockIdx.x, ks = blockIdx.y, e = blockIdx.z;
    int t = threadIdx.x;
    int k0 = ks * KSLICE;
    for (int i = t; i < 64 * K4; i += 256) {
        int r = i / K4, k4 = i % K4;
        *(float4*)&xs[r * SP + k4 * 4] =
            *(const float4*)(X + ((long)e * BB + r) * K + k0 + k4 * 4);
    }
    __syncthreads();
    int c = cb * 32 + (t & 7) * 4;
    int r0 = (t >> 3) * 2;
    const float* Wp = W + ((long)e * K + k0) * OUT + c;
    float acc0[4], acc1[4];
#pragma unroll
    for (int j = 0; j < 4; j++) {
        float bv = ADD_BIAS ? bias[(long)e * OUT + c + j] : 0.f;
        acc0[j] = bv;
        acc1[j] = bv;
    }
#pragma unroll 4
    for (int k4 = 0; k4 < K4; k4++) {
        float4 x0 = *(const float4*)&xs[r0 * SP + k4 * 4];
        float4 x1 = *(const float4*)&xs[(r0 + 1) * SP + k4 * 4];
        const float* xp0 = &x0.x;
        const float* xp1 = &x1.x;
#pragma unroll
        for (int j = 0; j < 4; j++) {
            float4 wv = *(const float4*)(Wp + (long)(k4 * 4 + j) * OUT);
            float xa = xp0[j], xb = xp1[j];
            acc0[0] += xa * wv.x; acc0[1] += xa * wv.y;
            acc0[2] += xa * wv.z; acc0[3] += xa * wv.w;
            acc1[0] += xb * wv.x; acc1[1] += xb * wv.y;
            acc1[2] += xb * wv.z; acc1[3] += xb * wv.w;
        }
    }
    float* yp = Yp + ((long)ks * (EE * BB) + (long)e * BB + r0) * OUT + c;
    *(float4*)yp         = make_float4(acc0[0], acc0[1], acc0[2], acc0[3]);
    *(float4*)(yp + OUT) = make_float4(acc1[0], acc1[1], acc1[2], acc1[3]);
}

template<int KS, bool HAS_BIAS>
__global__ __launch_bounds__(256)
void k_lnact(const float* __restrict__ Yp, const float* __restrict__ bias,
             const float* __restrict__ g, const float* __restrict__ be,
             float* __restrict__ Yo) {
    __shared__ float redS[4], redQ[4];
    int row = blockIdx.x, t = threadIdx.x;
    int e = row >> 6;
    float v[2];
#pragma unroll
    for (int j = 0; j < 2; j++) {
        int cj = t + j * 256;
        float s = HAS_BIAS ? bias[(long)e * HH + cj] : 0.f;
#pragma unroll
        for (int ks = 0; ks < KS; ks++)
            s += Yp[((long)ks * (EE * BB) + row) * HH + cj];
        v[j] = s;
    }
    float s = v[0] + v[1];
    float q = v[0] * v[0] + v[1] * v[1];
    for (int off = 32; off > 0; off >>= 1) {
        s += __shfl_xor(s, off);
        q += __shfl_xor(q, off);
    }
    int wave = t >> 6, lane = t & 63;
    if (lane == 0) { redS[wave] = s; redQ[wave] = q; }
    __syncthreads();
    float S = redS[0] + redS[1] + redS[2] + redS[3];
    float Q = redQ[0] + redQ[1] + redQ[2] + redQ[3];
    float mean = S * (1.f / HH);
    float var = Q * (1.f / HH) - mean * mean;
    float rstd = rsqrtf(var + LN_EPS);
#pragma unroll
    for (int j = 0; j < 2; j++) {
        int cj = t + j * 256;
        float gg = g[(long)e * HH + cj], bb = be[(long)e * HH + cj];
        Yo[(long)row * HH + cj] = mishf((v[j] - mean) * rstd * gg + bb);
    }
}

template<int KS>
__global__ __launch_bounds__(256)
void k_fin3(const float* __restrict__ p3, const float* __restrict__ b3,
            float* __restrict__ eout) {
    int t = threadIdx.x;
    int row = blockIdx.x * 2 + (t >> 7);
    int c = t & 127;
    int e = row >> 6, b = row & 63;
    float s = b3[(long)e * DZ + c];
#pragma unroll
    for (int ks = 0; ks < KS; ks++)
        s += p3[((long)ks * (EE * BB) + row) * DZ + c];
    eout[((long)b * EE + e) * DZ + c] = s;
}

// ---------------- K5: combine softmax over E + mix (vectorized stores) ----------------
__global__ __launch_bounds__(256)
void k_combine(const float* __restrict__ w, const float* __restrict__ eout,
               float* __restrict__ out) {
    __shared__ float comb[64][EE];
    __shared__ float eo[EE * DZ];
    int b = blockIdx.y, n0 = blockIdx.x * 64, t = threadIdx.x;
    for (int i = t; i < EE * DZ / 4; i += 256)
        ((float4*)eo)[i] = ((const float4*)(eout + (long)b * EE * DZ))[i];
    int tok = t >> 2, sub = t & 3;
    const float4 wv = *(const float4*)(w + ((long)b * NN + n0 + tok) * EE + sub * 4);
    float mx = fmaxf(fmaxf(wv.x, wv.y), fmaxf(wv.z, wv.w));
    mx = fmaxf(mx, __shfl_xor(mx, 1, 4));
    mx = fmaxf(mx, __shfl_xor(mx, 2, 4));
    float e0 = __expf(wv.x - mx), e1 = __expf(wv.y - mx);
    float e2 = __expf(wv.z - mx), e3 = __expf(wv.w - mx);
    float s = e0 + e1 + e2 + e3;
    s += __shfl_xor(s, 1, 4);
    s += __shfl_xor(s, 2, 4);
    float rs = 1.f / s;
    comb[tok][sub * 4 + 0] = e0 * rs;
    comb[tok][sub * 4 + 1] = e1 * rs;
    comb[tok][sub * 4 + 2] = e2 * rs;
    comb[tok][sub * 4 + 3] = e3 * rs;
    __syncthreads();

    for (int i = t; i < 64 * (DZ / 4); i += 256) {
        int tk = i >> 5, c4 = (i & 31) * 4;
        float ax = 0.f, ay = 0.f, az = 0.f, aw = 0.f;
#pragma unroll
        for (int e = 0; e < EE; e++) {
            float cw = comb[tk][e];
            float4 ev = *(const float4*)&eo[e * DZ + c4];
            ax += cw * ev.x; ay += cw * ev.y;
            az += cw * ev.z; aw += cw * ev.w;
        }
        *(float4*)&out[((long)b * NN + n0 + tk) * DZ + c4] = make_float4(ax, ay, az, aw);
    }
}

extern "C" void kernel_launch(void* const* d_in, const int* in_sizes, int n_in,
                              void* d_out, int out_size, void* d_ws, size_t ws_size,
                              hipStream_t stream) {
    const float* z   = (const float*)d_in[0];
    const float* a   = (const float*)d_in[1];
    const float* phi = (const float*)d_in[2];
    const float* W1  = (const float*)d_in[3];
    const float* b1  = (const float*)d_in[4];
    const float* g1  = (const float*)d_in[5];
    const float* be1 = (const float*)d_in[6];
    const float* W2  = (const float*)d_in[7];
    const float* b2  = (const float*)d_in[8];
    const float* g2  = (const float*)d_in[9];
    const float* be2 = (const float*)d_in[10];
    const float* W3  = (const float*)d_in[11];
    const float* b3  = (const float*)d_in[12];
    float* out = (float*)d_out;

    char* p = (char*)d_ws;
    float* w    = (float*)p; p += (size_t)BB * NN * EE * 4;          // 8.39 MB
    float* gmax = (float*)p; p += (size_t)BB * EE * 4;
    float* grcp = (float*)p; p += (size_t)BB * EE * 4;
    float* lmax = (float*)p; p += (size_t)BB * 4 * EE * 4;
    float* lsum = (float*)p; p += (size_t)BB * 4 * EE * 4;
    float* xin  = (float*)p; p += (size_t)BB * EE * DD * 4;          // 786 KB
    unsigned short* php = (unsigned short*)p; p += 6 * 64 * 8 * 2;   // 6 KB
    unsigned short* plp = (unsigned short*)p; p += 6 * 64 * 8 * 2;   // 6 KB
    float* pZ   = (float*)p; p += (size_t)NCH * BB * EE * 4;         // 131 KB
    float* Zg   = (float*)p; p += (size_t)BB * EE * 4;               // 4 KB
    // REGION: time-shared: pxin (NCH*786KB = 25.2 MB, phase A) vs
    // gemm partials + h1 + eout (~11 MB, phase B)
    char* region = p;
    float* pxin = (float*)region;
    float* part = (float*)region;
    float* h1   = (float*)(region + (size_t)4 * EE * BB * HH * 4);
    float* h2   = h1;
    float* eout = (float*)(region + (size_t)4 * EE * BB * HH * 4
                                  + (size_t)EE * BB * HH * 4);
    size_t region_off = (size_t)(region - (char*)d_ws);
    size_t need_full = region_off + (size_t)NCH * EE * BB * DD * 4;
    bool full = ws_size >= need_full;

    k_phipack<<<12, 256, 0, stream>>>(phi, php, plp);

    if (full) {
        k_wxin<<<dim3(NCH, BB), 256, 0, stream>>>(z, a, php, plp, w, pxin, pZ);
        k_zred<<<4, 256, 0, stream>>>(pZ, Zg);
        k_xinred<<<EE * BB * DD / 256, 256, 0, stream>>>(pxin, Zg, xin);
    } else {
        k_weights<<<BB * NN / 64, 256, 0, stream>>>(z, a, php, plp, w);
        k_stats1<<<dim3(4, BB), 256, 0, stream>>>(w, lmax, lsum);
        k_stats2<<<4, 256, 0, stream>>>(lmax, lsum, gmax, grcp);
        hipMemsetAsync(xin, 0, (size_t)BB * EE * DD * 4, stream);
        k_xin_scalar<<<dim3(NN / 128, BB), 192, 0, stream>>>(z, a, w, gmax, grcp, xin);
    }

    // layer 1: 192 -> 512, split-K 2
    k_gemm<DD, HH, 96, false>
        <<<dim3(HH / 32, 2, EE), 256, 0, stream>>>(xin, W1, nullptr, part);
    k_lnact<2, true><<<EE * BB, 256, 0, stream>>>(part, b1, g1, be1, h1);

    // layer 2: 512 -> 512, split-K 4
    k_gemm<HH, HH, 128, false>
        <<<dim3(HH / 32, 4, EE), 256, 0, stream>>>(h1, W2, nullptr, part);
    k_lnact<4, true><<<EE * BB, 256, 0, stream>>>(part, b2, g2, be2, h2);

    // layer 3: 512 -> 128, split-K 8
    k_gemm<HH, DZ, 64, false>
        <<<dim3(DZ / 32, 8, EE), 256, 0, stream>>>(h2, W3, nullptr, part);
    k_fin3<8><<<EE * BB / 2, 256, 0, stream>>>(part, b3, eout);

    k_combine<<<dim3(NN / 64, BB), 256, 0, stream>>>(w, eout, out);
}